// Round 17
// baseline (318.504 us; speedup 1.0000x reference)
//
#include <hip/hip_runtime.h>
#include <hip/hip_bf16.h>

typedef __bf16 bf16;
typedef __attribute__((ext_vector_type(4))) __bf16 bf16x4;
typedef __attribute__((ext_vector_type(8))) __bf16 bf16x8;
typedef __attribute__((ext_vector_type(4))) float f32x4;

#define MFMA16(a, b, c) __builtin_amdgcn_mfma_f32_16x16x32_bf16(a, b, c, 0, 0, 0)

#define LGKM_FENCE()                                      \
  do {                                                    \
    asm volatile("s_waitcnt lgkmcnt(0)" ::: "memory");    \
    __builtin_amdgcn_sched_barrier(0);                    \
  } while (0)

#define SCHED0() __builtin_amdgcn_sched_barrier(0)
#define SBAR() __builtin_amdgcn_s_barrier()
#define PRIO(x) __builtin_amdgcn_s_setprio(x)

typedef __attribute__((address_space(1))) void gvoid;
typedef __attribute__((address_space(3))) void lvoid;
__device__ __forceinline__ void gl16(const bf16* g, bf16* l) {
  __builtin_amdgcn_global_load_lds((gvoid*)g, (lvoid*)l, 16, 0, 0);
}

// Problem geometry: B=4, T=1024, D=1024, H=16, HD=64, DFF=4096, M=4096

// ---------------------------------------------------------------------------
// Fused preprocessing (R13-proven): one flat-grid dispatch.
// ---------------------------------------------------------------------------
struct PrepArgs {
  const float* wsq[8];
  const float* w1;
  const float* w2;
  const float* xe;
  const float* bs[5];
  bf16* wt8;
  bf16* w1t;
  bf16* w2t;
  bf16* xebf;
  float* bq3;
  float* bkv2;
};

__global__ __launch_bounds__(256) void prep_k(PrepArgs a) {
  __shared__ float t[32][33];
  const int blk = blockIdx.x, tid = threadIdx.x;
  const int tx = tid & 31, ty = tid >> 5;
  if (blk < 8192) {
    const int z = blk >> 10, b = blk & 1023;
    const float* w = a.wsq[z];
    bf16* wt = a.wt8 + ((size_t)z << 20);
    const int nb = (b & 31) * 32, kb = (b >> 5) * 32;
    for (int i = 0; i < 4; ++i)
      t[ty + i * 8][tx] = w[(size_t)(kb + ty + i * 8) * 1024 + nb + tx];
    __syncthreads();
    for (int i = 0; i < 4; ++i)
      wt[(size_t)(nb + ty + i * 8) * 1024 + kb + tx] = (bf16)t[tx][ty + i * 8];
  } else if (blk < 12288) {
    const int b = blk - 8192;
    const int nb = (b & 127) * 32, kb = (b >> 7) * 32;
    for (int i = 0; i < 4; ++i)
      t[ty + i * 8][tx] = a.w1[(size_t)(kb + ty + i * 8) * 4096 + nb + tx];
    __syncthreads();
    for (int i = 0; i < 4; ++i)
      a.w1t[(size_t)(nb + ty + i * 8) * 1024 + kb + tx] = (bf16)t[tx][ty + i * 8];
  } else if (blk < 16384) {
    const int b = blk - 12288;
    const int nb = (b & 31) * 32, kb = (b >> 5) * 32;
    for (int i = 0; i < 4; ++i)
      t[ty + i * 8][tx] = a.w2[(size_t)(kb + ty + i * 8) * 1024 + nb + tx];
    __syncthreads();
    for (int i = 0; i < 4; ++i)
      a.w2t[(size_t)(nb + ty + i * 8) * 4096 + kb + tx] = (bf16)t[tx][ty + i * 8];
  } else if (blk < 20480) {
    const int i = (blk - 16384) * 256 + tid;
    const float4 v = ((const float4*)a.xe)[i];
    bf16* o = a.xebf + (size_t)i * 4;
    o[0] = (bf16)v.x; o[1] = (bf16)v.y; o[2] = (bf16)v.z; o[3] = (bf16)v.w;
  } else {
    const int i = blk - 20480;
    float* d = (i < 3) ? a.bq3 + i * 1024 : a.bkv2 + (i - 3) * 1024;
    ((float4*)d)[tid] = ((const float4*)a.bs[i])[tid];
  }
}

// ---------------------------------------------------------------------------
// V transpose x2: Vp[M,1024] (head cols) -> Vt[B*H][64][1024].
// ---------------------------------------------------------------------------
__global__ __launch_bounds__(512) void vtrans_k(const bf16* __restrict__ V0,
                                                const bf16* __restrict__ V1,
                                                bf16* __restrict__ T0,
                                                bf16* __restrict__ T1) {
  const bf16* Vp = blockIdx.z ? V1 : V0;
  bf16* Vt = blockIdx.z ? T1 : T0;
  __shared__ bf16 tl[64][72];
  const int tt = blockIdx.x, bh = blockIdx.y;
  const int b = bh >> 4, h = bh & 15;
  const int tid = threadIdx.x;
  const int row = tid >> 3, ck = tid & 7;
  *(bf16x8*)&tl[row][ck * 8] =
      *(const bf16x8*)&Vp[(size_t)(b * 1024 + tt * 64 + row) * 1024 + h * 64 + ck * 8];
  __syncthreads();
  const int hd = tid >> 3, tc = tid & 7;
  bf16 tmp[8];
#pragma unroll
  for (int e = 0; e < 8; ++e) tmp[e] = tl[tc * 8 + e][hd];
  *(bf16x8*)&Vt[(size_t)(bh * 64 + hd) * 1024 + tt * 64 + tc * 8] = *(bf16x8*)tmp;
}

// ---------------------------------------------------------------------------
// LayerNorm over D=1024. TIN = float or bf16.
// ---------------------------------------------------------------------------
template <typename TIN>
__global__ __launch_bounds__(256) void ln_k(const TIN* __restrict__ x,
                                            const float* __restrict__ g,
                                            const float* __restrict__ bta,
                                            bf16* __restrict__ out) {
  const int row = blockIdx.x, tid = threadIdx.x;
  float v0, v1, v2, v3;
  if constexpr (sizeof(TIN) == 4) {
    const float4 v = ((const float4*)((const float*)x + (size_t)row * 1024))[tid];
    v0 = v.x; v1 = v.y; v2 = v.z; v3 = v.w;
  } else {
    const bf16x4 v = *(const bf16x4*)((const bf16*)x + (size_t)row * 1024 + tid * 4);
    v0 = (float)v[0]; v1 = (float)v[1]; v2 = (float)v[2]; v3 = (float)v[3];
  }
  float s = v0 + v1 + v2 + v3;
  float sq = v0 * v0 + v1 * v1 + v2 * v2 + v3 * v3;
  for (int d = 1; d < 64; d <<= 1) { s += __shfl_xor(s, d); sq += __shfl_xor(sq, d); }
  __shared__ float rs[4], rq[4];
  const int w = tid >> 6, lane = tid & 63;
  if (lane == 0) { rs[w] = s; rq[w] = sq; }
  __syncthreads();
  s = rs[0] + rs[1] + rs[2] + rs[3];
  sq = rq[0] + rq[1] + rq[2] + rq[3];
  const float mean = s * (1.0f / 1024.0f);
  const float var = sq * (1.0f / 1024.0f) - mean * mean;
  const float rstd = rsqrtf(var + 1e-5f);
  const float4 gv = ((const float4*)g)[tid];
  const float4 bv = ((const float4*)bta)[tid];
  bf16* o = out + (size_t)row * 1024 + tid * 4;
  o[0] = (bf16)((v0 - mean) * rstd * gv.x + bv.x);
  o[1] = (bf16)((v1 - mean) * rstd * gv.y + bv.y);
  o[2] = (bf16)((v2 - mean) * rstd * gv.z + bv.z);
  o[3] = (bf16)((v3 - mean) * rstd * gv.w + bv.w);
}

// ---------------------------------------------------------------------------
// GEMM 128x128, BK=64, 512 thr = 8 waves (4M x 2N, 32x64 out each),
// depth-2 counted-vmcnt dbuf, XOR-swizzled LDS. 16 waves/CU at 2 blocks/CU.
// No setprio (m190: negative on lockstep 2-phase GEMM).
// EPI: 3 = bias + exact GELU -> bf16 (MLP1).
// ---------------------------------------------------------------------------
template <int EPI>
__global__ __launch_bounds__(512) void gemm_k(const bf16* __restrict__ A,
                                              const bf16* __restrict__ Bt,
                                              const float* __restrict__ bias,
                                              void* __restrict__ o0,
                                              int K, int N) {
  __shared__ bf16 As[2][128 * 64];
  __shared__ bf16 Bs[2][128 * 64];
  const int tid = threadIdx.x;
  const int lane = tid & 63, w = tid >> 6;
  const int wr = w >> 1, wc = w & 1;  // 4M x 2N
  const int l15 = lane & 15, l4 = lane >> 4;
  const int gx = gridDim.x;
  const int nwg = gx * gridDim.y;
  const int flat = blockIdx.x + blockIdx.y * gx;
  const int swz = (flat & 7) * (nwg >> 3) + (flat >> 3);
  const size_t bm = swz / gx, bn = swz % gx;
  const bf16* Ab = A + bm * 128 * (size_t)K;
  const bf16* Bb = Bt + bn * 128 * (size_t)K;

  const f32x4 zero4 = {0.f, 0.f, 0.f, 0.f};
  f32x4 acc[2][4];
  for (int m = 0; m < 2; ++m)
    for (int n = 0; n < 4; ++n) acc[m][n] = zero4;

  const int srow = tid >> 3;                 // 0..63
  const int gck = ((tid & 7) ^ (srow & 7)) * 8;
  auto stage = [&](int buf, int t) {
    const int kt = t * 64;
    bf16* la = As[buf] + tid * 8;
    bf16* lb = Bs[buf] + tid * 8;
    gl16(Ab + (size_t)srow * K + kt + gck, la);
    gl16(Ab + (size_t)(srow + 64) * K + kt + gck, la + 4096);
    gl16(Bb + (size_t)srow * K + kt + gck, lb);
    gl16(Bb + (size_t)(srow + 64) * K + kt + gck, lb + 4096);
  };
  const int xr = l15 & 7;
  const int c0 = (l4 ^ xr) * 8, c1 = ((4 + l4) ^ xr) * 8;
  auto compute = [&](int buf) {
    bf16x8 af[2][2], bfr[4][2];
    for (int m = 0; m < 2; ++m) {
      const int ro = (wr * 32 + m * 16 + l15) * 64;
      af[m][0] = *(const bf16x8*)&As[buf][ro + c0];
      af[m][1] = *(const bf16x8*)&As[buf][ro + c1];
    }
    for (int n = 0; n < 4; ++n) {
      const int ro = (wc * 64 + n * 16 + l15) * 64;
      bfr[n][0] = *(const bf16x8*)&Bs[buf][ro + c0];
      bfr[n][1] = *(const bf16x8*)&Bs[buf][ro + c1];
    }
    for (int m = 0; m < 2; ++m)
      for (int n = 0; n < 4; ++n) {
        acc[m][n] = MFMA16(af[m][0], bfr[n][0], acc[m][n]);
        acc[m][n] = MFMA16(af[m][1], bfr[n][1], acc[m][n]);
      }
  };

  const int nt = K >> 6;
  stage(0, 0);
  stage(1, 1);
  int cur = 0;
  for (int t = 0; t < nt - 2; ++t) {
    asm volatile("s_waitcnt vmcnt(4)" ::: "memory");
    SBAR(); SCHED0();
    compute(cur);
    SCHED0(); SBAR(); SCHED0();
    stage(cur, t + 2);
    cur ^= 1;
  }
  asm volatile("s_waitcnt vmcnt(4)" ::: "memory");
  SBAR(); SCHED0();
  compute(cur);
  cur ^= 1;
  asm volatile("s_waitcnt vmcnt(0)" ::: "memory");
  SBAR(); SCHED0();
  compute(cur);

  for (int m = 0; m < 2; ++m) {
    const int row0 = (int)bm * 128 + wr * 32 + m * 16 + l4 * 4;
    for (int n = 0; n < 4; ++n) {
      const int col = (int)bn * 128 + wc * 64 + n * 16 + l15;
      const float bv = bias[col];
      for (int r = 0; r < 4; ++r) {
        const int row = row0 + r;
        const float v = acc[m][n][r] + bv;
        const float gl = 0.5f * v * (1.0f + erff(v * 0.70710678118f));
        ((bf16*)o0)[(size_t)row * N + col] = (bf16)gl;
      }
    }
  }
}

// ---------------------------------------------------------------------------
// Fused QKV(N=3072) + cross-KV(N=2048), same 8-wave 128x128 structure.
// Grid (40, 32). No setprio.
// ---------------------------------------------------------------------------
__global__ __launch_bounds__(512) void gemmqkv_k(const bf16* __restrict__ Aln,
                                                 const bf16* __restrict__ Axe,
                                                 const bf16* __restrict__ wtq,
                                                 const bf16* __restrict__ wtkv,
                                                 const float* __restrict__ bq3,
                                                 const float* __restrict__ bkv2,
                                                 bf16* __restrict__ Qb,
                                                 bf16* __restrict__ Kb1,
                                                 bf16* __restrict__ Vp1,
                                                 bf16* __restrict__ Kb2,
                                                 bf16* __restrict__ Vp2) {
  const int K = 1024;
  __shared__ bf16 As[2][128 * 64];
  __shared__ bf16 Bs[2][128 * 64];
  const int tid = threadIdx.x;
  const int lane = tid & 63, w = tid >> 6;
  const int wr = w >> 1, wc = w & 1;
  const int l15 = lane & 15, l4 = lane >> 4;
  const int gx = 40;
  const int nwg = 40 * 32;
  const int flat = blockIdx.x + blockIdx.y * gx;
  const int swz = (flat & 7) * (nwg >> 3) + (flat >> 3);
  const size_t bm = swz / gx, bn = swz % gx;
  const bool qkv = bn < 24;
  const bf16* Ab = (qkv ? Aln : Axe) + bm * 128 * (size_t)K;
  const bf16* Bb = qkv ? (wtq + bn * 128 * (size_t)K)
                       : (wtkv + (bn - 24) * 128 * (size_t)K);

  const f32x4 zero4 = {0.f, 0.f, 0.f, 0.f};
  f32x4 acc[2][4];
  for (int m = 0; m < 2; ++m)
    for (int n = 0; n < 4; ++n) acc[m][n] = zero4;

  const int srow = tid >> 3;
  const int gck = ((tid & 7) ^ (srow & 7)) * 8;
  auto stage = [&](int buf, int t) {
    const int kt = t * 64;
    bf16* la = As[buf] + tid * 8;
    bf16* lb = Bs[buf] + tid * 8;
    gl16(Ab + (size_t)srow * K + kt + gck, la);
    gl16(Ab + (size_t)(srow + 64) * K + kt + gck, la + 4096);
    gl16(Bb + (size_t)srow * K + kt + gck, lb);
    gl16(Bb + (size_t)(srow + 64) * K + kt + gck, lb + 4096);
  };
  const int xr = l15 & 7;
  const int c0 = (l4 ^ xr) * 8, c1 = ((4 + l4) ^ xr) * 8;
  auto compute = [&](int buf) {
    bf16x8 af[2][2], bfr[4][2];
    for (int m = 0; m < 2; ++m) {
      const int ro = (wr * 32 + m * 16 + l15) * 64;
      af[m][0] = *(const bf16x8*)&As[buf][ro + c0];
      af[m][1] = *(const bf16x8*)&As[buf][ro + c1];
    }
    for (int n = 0; n < 4; ++n) {
      const int ro = (wc * 64 + n * 16 + l15) * 64;
      bfr[n][0] = *(const bf16x8*)&Bs[buf][ro + c0];
      bfr[n][1] = *(const bf16x8*)&Bs[buf][ro + c1];
    }
    for (int m = 0; m < 2; ++m)
      for (int n = 0; n < 4; ++n) {
        acc[m][n] = MFMA16(af[m][0], bfr[n][0], acc[m][n]);
        acc[m][n] = MFMA16(af[m][1], bfr[n][1], acc[m][n]);
      }
  };

  const int nt = K >> 6;
  stage(0, 0);
  stage(1, 1);
  int cur = 0;
  for (int t = 0; t < nt - 2; ++t) {
    asm volatile("s_waitcnt vmcnt(4)" ::: "memory");
    SBAR(); SCHED0();
    compute(cur);
    SCHED0(); SBAR(); SCHED0();
    stage(cur, t + 2);
    cur ^= 1;
  }
  asm volatile("s_waitcnt vmcnt(4)" ::: "memory");
  SBAR(); SCHED0();
  compute(cur);
  cur ^= 1;
  asm volatile("s_waitcnt vmcnt(0)" ::: "memory");
  SBAR(); SCHED0();
  compute(cur);

  for (int m = 0; m < 2; ++m) {
    const int row0 = (int)bm * 128 + wr * 32 + m * 16 + l4 * 4;
    for (int n = 0; n < 4; ++n) {
      const int coln = (qkv ? (int)bn : (int)bn - 24) * 128 + wc * 64 + n * 16 + l15;
      const float bv = qkv ? bq3[coln] : bkv2[coln];
      const int which = coln >> 10, c = coln & 1023;
      bf16* op = qkv ? (which == 0 ? Qb : (which == 1 ? Kb1 : Vp1))
                     : (which == 0 ? Kb2 : Vp2);
      for (int r = 0; r < 4; ++r) {
        const int row = row0 + r;
        op[(size_t)row * 1024 + c] = (bf16)(acc[m][n][r] + bv);
      }
    }
  }
}

// ---------------------------------------------------------------------------
// GEMM 128x64, BK=64, 512 thr = 8 waves (each 16x64 out), depth-2 counted
// vmcnt(3) dbuf. No setprio. EPI: 0 bias->bf16 | 2 +res(f32)->bf16 |
// 4 +res(bf16)->bf16 | 5 +res(bf16)->fp32
// ---------------------------------------------------------------------------
template <int EPI>
__global__ __launch_bounds__(512) void gemm64_k(const bf16* __restrict__ A,
                                                const bf16* __restrict__ Bt,
                                                const float* __restrict__ bias,
                                                const void* __restrict__ res,
                                                void* __restrict__ o0,
                                                int K, int N) {
  __shared__ bf16 As[2][128 * 64];
  __shared__ bf16 Bs[2][64 * 64];
  const int tid = threadIdx.x;
  const int lane = tid & 63, w = tid >> 6;
  const int l15 = lane & 15, l4 = lane >> 4;
  const int gx = gridDim.x;
  const int nwg = gx * gridDim.y;
  const int flat = blockIdx.x + blockIdx.y * gx;
  const int swz = (flat & 7) * (nwg >> 3) + (flat >> 3);
  const size_t bm = swz / gx, bn = swz % gx;
  const bf16* Ab = A + bm * 128 * (size_t)K;
  const bf16* Bb = Bt + bn * 64 * (size_t)K;

  const f32x4 zero4 = {0.f, 0.f, 0.f, 0.f};
  f32x4 acc[4];
  for (int n = 0; n < 4; ++n) acc[n] = zero4;

  const int srow = tid >> 3;
  const int gck = ((tid & 7) ^ (srow & 7)) * 8;
  auto stage = [&](int buf, int t) {
    const int kt = t * 64;
    bf16* la = As[buf] + tid * 8;
    gl16(Ab + (size_t)srow * K + kt + gck, la);
    gl16(Ab + (size_t)(srow + 64) * K + kt + gck, la + 4096);
    gl16(Bb + (size_t)srow * K + kt + gck, Bs[buf] + tid * 8);
  };
  const int xr = l15 & 7;
  const int c0 = (l4 ^ xr) * 8, c1 = ((4 + l4) ^ xr) * 8;
  auto compute = [&](int buf) {
    bf16x8 af[2], bfr[4][2];
    {
      const int ro = (w * 16 + l15) * 64;
      af[0] = *(const bf16x8*)&As[buf][ro + c0];
      af[1] = *(const bf16x8*)&As[buf][ro + c1];
    }
    for (int n = 0; n < 4; ++n) {
      const int ro = (n * 16 + l15) * 64;
      bfr[n][0] = *(const bf16x8*)&Bs[buf][ro + c0];
      bfr[n][1] = *(const bf16x8*)&Bs[buf][ro + c1];
    }
    for (int n = 0; n < 4; ++n) {
      acc[n] = MFMA16(af[0], bfr[n][0], acc[n]);
      acc[n] = MFMA16(af[1], bfr[n][1], acc[n]);
    }
  };

  const int nt = K >> 6;
  stage(0, 0);
  stage(1, 1);
  int cur = 0;
  for (int t = 0; t < nt - 2; ++t) {
    asm volatile("s_waitcnt vmcnt(3)" ::: "memory");
    SBAR(); SCHED0();
    compute(cur);
    SCHED0(); SBAR(); SCHED0();
    stage(cur, t + 2);
    cur ^= 1;
  }
  asm volatile("s_waitcnt vmcnt(3)" ::: "memory");
  SBAR(); SCHED0();
  compute(cur);
  cur ^= 1;
  asm volatile("s_waitcnt vmcnt(0)" ::: "memory");
  SBAR(); SCHED0();
  compute(cur);

  const int row0 = (int)bm * 128 + w * 16 + l4 * 4;
  for (int n = 0; n < 4; ++n) {
    const int col = (int)bn * 64 + n * 16 + l15;
    const float bv = bias[col];
    for (int r = 0; r < 4; ++r) {
      const int row = row0 + r;
      const size_t idx = (size_t)row * N + col;
      float v = acc[n][r] + bv;
      if constexpr (EPI == 0) {
        ((bf16*)o0)[idx] = (bf16)v;
      } else if constexpr (EPI == 2) {
        v += ((const float*)res)[idx];
        ((bf16*)o0)[idx] = (bf16)v;
      } else if constexpr (EPI == 4) {
        v += (float)((const bf16*)res)[idx];
        ((bf16*)o0)[idx] = (bf16)v;
      } else {
        v += (float)((const bf16*)res)[idx];
        ((float*)o0)[idx] = v;
      }
    }
  }
}

// ---------------------------------------------------------------------------
// Causal flash attention with cooperative LDS K/V staging (unchanged;
// setprio kept: m191 measured positive on attn).
// ---------------------------------------------------------------------------
__global__ __launch_bounds__(512) void attn_k(const bf16* __restrict__ Q,
                                              const bf16* __restrict__ Kb,
                                              const bf16* __restrict__ Vt,
                                              bf16* __restrict__ O) {
  __shared__ bf16 Ks[2][64 * 64];
  __shared__ bf16 Vs[2][64 * 64];
  __shared__ bf16 Plds[8][16][72];
  const int bx = blockIdx.x, bh = blockIdx.y;
  const int b = bh >> 4, h = bh & 15;
  const int tid = threadIdx.x, lane = tid & 63, w = tid >> 6;
  const int myqt = (w < 4) ? bx : (15 - bx);
  const int qbase = myqt * 64 + (w & 3) * 16;
  const int l15 = lane & 15, l4 = lane >> 4;
  const int nt = 16 - bx;

  const bf16* Qp = Q + (size_t)(b * 1024 + qbase + l15) * 1024 + h * 64 + l4 * 8;
  bf16x8 qf0 = *(const bf16x8*)Qp;
  bf16x8 qf1 = *(const bf16x8*)(Qp + 32);
  for (int i = 0; i < 8; ++i) {
    qf0[i] = (bf16)((float)qf0[i] * 0.125f);
    qf1[i] = (bf16)((float)qf1[i] * 0.125f);
  }
  bf16x8 onesf;
  for (int i = 0; i < 8; ++i) onesf[i] = (bf16)1.0f;

  const f32x4 zero4 = {0.f, 0.f, 0.f, 0.f};
  f32x4 o[4], ol;
  float mrow[4];
  for (int d = 0; d < 4; ++d) o[d] = zero4;
  ol = zero4;
  for (int r = 0; r < 4; ++r) mrow[r] = -1e30f;

  const int qrow0 = qbase + l4 * 4;

  const int srow = tid >> 3;
  const int cg = (tid & 7) ^ (srow & 7);
  const bf16* Kg = Kb + (size_t)(b * 1024 + srow) * 1024 + h * 64 + cg * 8;
  const bf16* Vg = Vt + (size_t)(bh * 64 + srow) * 1024 + cg * 8;
  auto stage = [&](int buf, int t) {
    gl16(Kg + (size_t)t * 64 * 1024, Ks[buf] + tid * 8);
    gl16(Vg + t * 64, Vs[buf] + tid * 8);
  };

  const int xr = l15 & 7;
  const int fc0 = (l4 ^ xr) * 8, fc1 = ((4 + l4) ^ xr) * 8;

  auto compute = [&](int buf, int kt) {
    const int kbase = kt * 64;
    f32x4 s[4];
    for (int n = 0; n < 4; ++n) s[n] = zero4;
    PRIO(1);
    for (int n = 0; n < 4; ++n) {
      const int ro = (n * 16 + l15) * 64;
      const bf16x8 kf0 = *(const bf16x8*)&Ks[buf][ro + fc0];
      const bf16x8 kf1 = *(const bf16x8*)&Ks[buf][ro + fc1];
      s[n] = MFMA16(qf0, kf0, s[n]);
      s[n] = MFMA16(qf1, kf1, s[n]);
    }
    PRIO(0);
    if (kt == myqt) {
      for (int n = 0; n < 4; ++n) {
        const int kc = kbase + n * 16 + l15;
        for (int r = 0; r < 4; ++r)
          if (kc > qrow0 + r) s[n][r] = -1e30f;
      }
    }
    float mx[4];
    for (int r = 0; r < 4; ++r)
      mx[r] = fmaxf(fmaxf(s[0][r], s[1][r]), fmaxf(s[2][r], s[3][r]));
    for (int d0 = 1; d0 < 16; d0 <<= 1)
      for (int r = 0; r < 4; ++r) mx[r] = fmaxf(mx[r], __shfl_xor(mx[r], d0));
    float alpha[4];
    for (int r = 0; r < 4; ++r) {
      const float mnew = fmaxf(mrow[r], mx[r]);
      alpha[r] = __expf(mrow[r] - mnew);
      mrow[r] = mnew;
    }
    for (int n = 0; n < 4; ++n)
      for (int r = 0; r < 4; ++r) s[n][r] = __expf(s[n][r] - mrow[r]);
    for (int d = 0; d < 4; ++d)
      for (int r = 0; r < 4; ++r) o[d][r] *= alpha[r];
    for (int r = 0; r < 4; ++r) ol[r] *= alpha[r];

    LGKM_FENCE();
    for (int r = 0; r < 4; ++r)
      for (int n = 0; n < 4; ++n)
        Plds[w][l4 * 4 + r][n * 16 + l15] = (bf16)s[n][r];
    LGKM_FENCE();
    const bf16x8 pf0 = *(const bf16x8*)&Plds[w][l15][l4 * 8];
    const bf16x8 pf1 = *(const bf16x8*)&Plds[w][l15][32 + l4 * 8];

    PRIO(1);
    for (int d = 0; d < 4; ++d) {
      const int ro = (d * 16 + l15) * 64;
      const bf16x8 vf0 = *(const bf16x8*)&Vs[buf][ro + fc0];
      const bf16x8 vf1 = *(const bf16x8*)&Vs[buf][ro + fc1];
      o[d] = MFMA16(pf0, vf0, o[d]);
      o[d] = MFMA16(pf1, vf1, o[d]);
    }
    ol = MFMA16(pf0, onesf, ol);
    ol = MFMA16(pf1, onesf, ol);
    PRIO(0);
  };

  stage(0, 0);
  stage(1, 1);
  int cur = 0;
  for (int t = 0; t < nt - 2; ++t) {
    asm volatile("s_waitcnt vmcnt(2)" ::: "memory");
    SBAR(); SCHED0();
    if (t <= myqt) compute(cur, t);
    SCHED0(); SBAR(); SCHED0();
    stage(cur, t + 2);
    cur ^= 1;
  }
  asm volatile("s_waitcnt vmcnt(2)" ::: "memory");
  SBAR(); SCHED0();
  if (nt - 2 <= myqt) compute(cur, nt - 2);
  cur ^= 1;
  asm volatile("s_waitcnt vmcnt(0)" ::: "memory");
  SBAR(); SCHED0();
  if (nt - 1 <= myqt) compute(cur, nt - 1);

  for (int r = 0; r < 4; ++r) {
    const float inv = 1.0f / ol[r];
    for (int d = 0; d < 4; ++d) {
      O[(size_t)(b * 1024 + qbase + l4 * 4 + r) * 1024 + h * 64 + d * 16 + l15] =
          (bf16)(o[d][r] * inv);
    }
  }
}

// ---------------------------------------------------------------------------
extern "C" void kernel_launch(void* const* d_in, const int* in_sizes, int n_in,
                              void* d_out, int out_size, void* d_ws, size_t ws_size,
                              hipStream_t stream) {
  const float* x_enc = (const float*)d_in[0];
  const float* x     = (const float*)d_in[1];
  const float* ln1_g = (const float*)d_in[2];
  const float* ln1_b = (const float*)d_in[3];
  const float* ln2_g = (const float*)d_in[4];
  const float* ln2_b = (const float*)d_in[5];
  const float* sa_wq = (const float*)d_in[6];  const float* sa_bq = (const float*)d_in[7];
  const float* sa_wk = (const float*)d_in[8];  const float* sa_bk = (const float*)d_in[9];
  const float* sa_wv = (const float*)d_in[10]; const float* sa_bv = (const float*)d_in[11];
  const float* sa_wo = (const float*)d_in[12]; const float* sa_bo = (const float*)d_in[13];
  const float* ca_wq = (const float*)d_in[14]; const float* ca_bq = (const float*)d_in[15];
  const float* ca_wk = (const float*)d_in[16]; const float* ca_bk = (const float*)d_in[17];
  const float* ca_wv = (const float*)d_in[18]; const float* ca_bv = (const float*)d_in[19];
  const float* ca_wo = (const float*)d_in[20]; const float* ca_bo = (const float*)d_in[21];
  const float* mlp_w1 = (const float*)d_in[22]; const float* mlp_b1 = (const float*)d_in[23];
  const float* mlp_w2 = (const float*)d_in[24]; const float* mlp_b2 = (const float*)d_in[25];

  char* ws = (char*)d_ws;
  size_t off = 0;
  auto take = [&](size_t bytes) { char* p = ws + off; off += (bytes + 255) & ~(size_t)255; return p; };

  bf16* wt8 = (bf16*)take((size_t)8 * 1024 * 1024 * 2);
  bf16* w1t   = (bf16*)take((size_t)4096 * 1024 * 2);
  bf16* w2t   = (bf16*)take((size_t)1024 * 4096 * 2);
  bf16* lnbuf = (bf16*)take((size_t)4096 * 1024 * 2);
  bf16* xe_bf = (bf16*)take((size_t)4096 * 1024 * 2);
  bf16* Qb    = (bf16*)take((size_t)4096 * 1024 * 2);
  bf16* Kb1   = (bf16*)take((size_t)4096 * 1024 * 2);
  bf16* Vp1   = (bf16*)take((size_t)4096 * 1024 * 2);
  bf16* Vt1   = (bf16*)take((size_t)4096 * 1024 * 2);
  bf16* Kb2   = (bf16*)take((size_t)4096 * 1024 * 2);
  bf16* Vp2   = (bf16*)take((size_t)4096 * 1024 * 2);
  bf16* Vt2   = (bf16*)take((size_t)4096 * 1024 * 2);
  bf16* AOb   = (bf16*)take((size_t)4096 * 1024 * 2);
  bf16* x1    = (bf16*)take((size_t)4096 * 1024 * 2);
  bf16* x2    = (bf16*)take((size_t)4096 * 1024 * 2);
  bf16* Hb    = (bf16*)take((size_t)4096 * 4096 * 2);
  float* bq3  = (float*)take((size_t)3072 * 4);
  float* bkv2 = (float*)take((size_t)2048 * 4);

  bf16* wt[8];
  for (int i = 0; i < 8; ++i) wt[i] = wt8 + (size_t)i * 1024 * 1024;

  const dim3 blk(256);
  PrepArgs pa;
  pa.wsq[0] = sa_wq; pa.wsq[1] = sa_wk; pa.wsq[2] = sa_wv; pa.wsq[3] = sa_wo;
  pa.wsq[4] = ca_wq; pa.wsq[5] = ca_wk; pa.wsq[6] = ca_wv; pa.wsq[7] = ca_wo;
  pa.w1 = mlp_w1; pa.w2 = mlp_w2; pa.xe = x_enc;
  pa.bs[0] = sa_bq; pa.bs[1] = sa_bk; pa.bs[2] = sa_bv;
  pa.bs[3] = ca_bk; pa.bs[4] = ca_bv;
  pa.wt8 = wt8; pa.w1t = w1t; pa.w2t = w2t; pa.xebf = xe_bf;
  pa.bq3 = bq3; pa.bkv2 = bkv2;
  prep_k<<<20485, blk, 0, stream>>>(pa);

  // ln1(x); fused [self QKV | cross KV]; both V transposes
  ln_k<float><<<4096, blk, 0, stream>>>(x, ln1_g, ln1_b, lnbuf);
  gemmqkv_k<<<dim3(40, 32), dim3(512), 0, stream>>>(lnbuf, xe_bf, wt[0], wt[5],
                                                    bq3, bkv2, Qb, Kb1, Vp1, Kb2, Vp2);
  vtrans_k<<<dim3(16, 64, 2), dim3(512), 0, stream>>>(Vp1, Vp2, Vt1, Vt2);

  // x1 = x + SelfAttn
  attn_k<<<dim3(8, 64), dim3(512), 0, stream>>>(Qb, Kb1, Vt1, AOb);
  gemm64_k<2><<<dim3(16, 32), dim3(512), 0, stream>>>(AOb, wt[3], sa_bo, x, x1, 1024, 1024);

  // x2 = x1 + CrossAttn(ln1(x1), x_encoder)
  ln_k<bf16><<<4096, blk, 0, stream>>>(x1, ln1_g, ln1_b, lnbuf);
  gemm64_k<0><<<dim3(16, 32), dim3(512), 0, stream>>>(lnbuf, wt[4], ca_bq, nullptr, Qb, 1024, 1024);
  attn_k<<<dim3(8, 64), dim3(512), 0, stream>>>(Qb, Kb2, Vt2, AOb);
  gemm64_k<4><<<dim3(16, 32), dim3(512), 0, stream>>>(AOb, wt[7], ca_bo, x1, x2, 1024, 1024);

  // out = x2 + MLP(ln2(x2))
  ln_k<bf16><<<4096, blk, 0, stream>>>(x2, ln2_g, ln2_b, lnbuf);
  gemm_k<3><<<dim3(32, 32), dim3(512), 0, stream>>>(lnbuf, w1t, mlp_b1, Hb, 1024, 4096);
  gemm64_k<5><<<dim3(16, 32), dim3(512), 0, stream>>>(Hb, w2t, mlp_b2, x2,
                                                      (float*)d_out, 4096, 1024);

  (void)in_sizes; (void)n_in; (void)out_size; (void)ws_size;
}

// Round 18
// 304.926 us; speedup vs baseline: 1.0445x; 1.0445x over previous
//
#include <hip/hip_runtime.h>
#include <hip/hip_bf16.h>

typedef __bf16 bf16;
typedef __attribute__((ext_vector_type(4))) __bf16 bf16x4;
typedef __attribute__((ext_vector_type(8))) __bf16 bf16x8;
typedef __attribute__((ext_vector_type(4))) float f32x4;

#define MFMA16(a, b, c) __builtin_amdgcn_mfma_f32_16x16x32_bf16(a, b, c, 0, 0, 0)

#define LGKM_FENCE()                                      \
  do {                                                    \
    asm volatile("s_waitcnt lgkmcnt(0)" ::: "memory");    \
    __builtin_amdgcn_sched_barrier(0);                    \
  } while (0)

#define SCHED0() __builtin_amdgcn_sched_barrier(0)
#define SBAR() __builtin_amdgcn_s_barrier()
#define PRIO(x) __builtin_amdgcn_s_setprio(x)

typedef __attribute__((address_space(1))) void gvoid;
typedef __attribute__((address_space(3))) void lvoid;
__device__ __forceinline__ void gl16(const bf16* g, bf16* l) {
  __builtin_amdgcn_global_load_lds((gvoid*)g, (lvoid*)l, 16, 0, 0);
}

// L2-aware XCD supertile: flat block id -> (bm, bn). Requires gy == 32 and
// nwg/(8*gx) == 4 (true for all GEMM grids here). Each XCD walks 4x4
// supertiles: working set 4 A-panels + 4 B-panels = 2MB < 4MB L2.
__device__ __forceinline__ void xcd_map(int flat, int* bm, int* bn) {
  const int xcd = flat & 7, local = flat >> 3;
  const int sup = local >> 4, s = local & 15;
  *bm = xcd * 4 + (s >> 2);
  *bn = sup * 4 + (s & 3);
}

// Problem geometry: B=4, T=1024, D=1024, H=16, HD=64, DFF=4096, M=4096

// ---------------------------------------------------------------------------
// Fused preprocessing (R13-proven): one flat-grid dispatch.
// ---------------------------------------------------------------------------
struct PrepArgs {
  const float* wsq[8];
  const float* w1;
  const float* w2;
  const float* xe;
  const float* bs[5];
  bf16* wt8;
  bf16* w1t;
  bf16* w2t;
  bf16* xebf;
  float* bq3;
  float* bkv2;
};

__global__ __launch_bounds__(256) void prep_k(PrepArgs a) {
  __shared__ float t[32][33];
  const int blk = blockIdx.x, tid = threadIdx.x;
  const int tx = tid & 31, ty = tid >> 5;
  if (blk < 8192) {
    const int z = blk >> 10, b = blk & 1023;
    const float* w = a.wsq[z];
    bf16* wt = a.wt8 + ((size_t)z << 20);
    const int nb = (b & 31) * 32, kb = (b >> 5) * 32;
    for (int i = 0; i < 4; ++i)
      t[ty + i * 8][tx] = w[(size_t)(kb + ty + i * 8) * 1024 + nb + tx];
    __syncthreads();
    for (int i = 0; i < 4; ++i)
      wt[(size_t)(nb + ty + i * 8) * 1024 + kb + tx] = (bf16)t[tx][ty + i * 8];
  } else if (blk < 12288) {
    const int b = blk - 8192;
    const int nb = (b & 127) * 32, kb = (b >> 7) * 32;
    for (int i = 0; i < 4; ++i)
      t[ty + i * 8][tx] = a.w1[(size_t)(kb + ty + i * 8) * 4096 + nb + tx];
    __syncthreads();
    for (int i = 0; i < 4; ++i)
      a.w1t[(size_t)(nb + ty + i * 8) * 1024 + kb + tx] = (bf16)t[tx][ty + i * 8];
  } else if (blk < 16384) {
    const int b = blk - 12288;
    const int nb = (b & 31) * 32, kb = (b >> 5) * 32;
    for (int i = 0; i < 4; ++i)
      t[ty + i * 8][tx] = a.w2[(size_t)(kb + ty + i * 8) * 1024 + nb + tx];
    __syncthreads();
    for (int i = 0; i < 4; ++i)
      a.w2t[(size_t)(nb + ty + i * 8) * 4096 + kb + tx] = (bf16)t[tx][ty + i * 8];
  } else if (blk < 20480) {
    const int i = (blk - 16384) * 256 + tid;
    const float4 v = ((const float4*)a.xe)[i];
    bf16* o = a.xebf + (size_t)i * 4;
    o[0] = (bf16)v.x; o[1] = (bf16)v.y; o[2] = (bf16)v.z; o[3] = (bf16)v.w;
  } else {
    const int i = blk - 20480;
    float* d = (i < 3) ? a.bq3 + i * 1024 : a.bkv2 + (i - 3) * 1024;
    ((float4*)d)[tid] = ((const float4*)a.bs[i])[tid];
  }
}

// ---------------------------------------------------------------------------
// V transpose x2: Vp[M,1024] (head cols) -> Vt[B*H][64][1024].
// ---------------------------------------------------------------------------
__global__ __launch_bounds__(512) void vtrans_k(const bf16* __restrict__ V0,
                                                const bf16* __restrict__ V1,
                                                bf16* __restrict__ T0,
                                                bf16* __restrict__ T1) {
  const bf16* Vp = blockIdx.z ? V1 : V0;
  bf16* Vt = blockIdx.z ? T1 : T0;
  __shared__ bf16 tl[64][72];
  const int tt = blockIdx.x, bh = blockIdx.y;
  const int b = bh >> 4, h = bh & 15;
  const int tid = threadIdx.x;
  const int row = tid >> 3, ck = tid & 7;
  *(bf16x8*)&tl[row][ck * 8] =
      *(const bf16x8*)&Vp[(size_t)(b * 1024 + tt * 64 + row) * 1024 + h * 64 + ck * 8];
  __syncthreads();
  const int hd = tid >> 3, tc = tid & 7;
  bf16 tmp[8];
#pragma unroll
  for (int e = 0; e < 8; ++e) tmp[e] = tl[tc * 8 + e][hd];
  *(bf16x8*)&Vt[(size_t)(bh * 64 + hd) * 1024 + tt * 64 + tc * 8] = *(bf16x8*)tmp;
}

// ---------------------------------------------------------------------------
// LayerNorm over D=1024. TIN = float or bf16.
// ---------------------------------------------------------------------------
template <typename TIN>
__global__ __launch_bounds__(256) void ln_k(const TIN* __restrict__ x,
                                            const float* __restrict__ g,
                                            const float* __restrict__ bta,
                                            bf16* __restrict__ out) {
  const int row = blockIdx.x, tid = threadIdx.x;
  float v0, v1, v2, v3;
  if constexpr (sizeof(TIN) == 4) {
    const float4 v = ((const float4*)((const float*)x + (size_t)row * 1024))[tid];
    v0 = v.x; v1 = v.y; v2 = v.z; v3 = v.w;
  } else {
    const bf16x4 v = *(const bf16x4*)((const bf16*)x + (size_t)row * 1024 + tid * 4);
    v0 = (float)v[0]; v1 = (float)v[1]; v2 = (float)v[2]; v3 = (float)v[3];
  }
  float s = v0 + v1 + v2 + v3;
  float sq = v0 * v0 + v1 * v1 + v2 * v2 + v3 * v3;
  for (int d = 1; d < 64; d <<= 1) { s += __shfl_xor(s, d); sq += __shfl_xor(sq, d); }
  __shared__ float rs[4], rq[4];
  const int w = tid >> 6, lane = tid & 63;
  if (lane == 0) { rs[w] = s; rq[w] = sq; }
  __syncthreads();
  s = rs[0] + rs[1] + rs[2] + rs[3];
  sq = rq[0] + rq[1] + rq[2] + rq[3];
  const float mean = s * (1.0f / 1024.0f);
  const float var = sq * (1.0f / 1024.0f) - mean * mean;
  const float rstd = rsqrtf(var + 1e-5f);
  const float4 gv = ((const float4*)g)[tid];
  const float4 bv = ((const float4*)bta)[tid];
  bf16* o = out + (size_t)row * 1024 + tid * 4;
  o[0] = (bf16)((v0 - mean) * rstd * gv.x + bv.x);
  o[1] = (bf16)((v1 - mean) * rstd * gv.y + bv.y);
  o[2] = (bf16)((v2 - mean) * rstd * gv.z + bv.z);
  o[3] = (bf16)((v3 - mean) * rstd * gv.w + bv.w);
}

// ---------------------------------------------------------------------------
// GEMM 128x128, BK=64, 512 thr = 8 waves (4M x 2N, 32x64 out each),
// depth-2 counted-vmcnt dbuf, XOR-swizzled LDS, L2 supertile map.
// EPI: 3 = bias + exact GELU -> bf16 (MLP1).
// ---------------------------------------------------------------------------
template <int EPI>
__global__ __launch_bounds__(512) void gemm_k(const bf16* __restrict__ A,
                                              const bf16* __restrict__ Bt,
                                              const float* __restrict__ bias,
                                              void* __restrict__ o0,
                                              int K, int N) {
  __shared__ bf16 As[2][128 * 64];
  __shared__ bf16 Bs[2][128 * 64];
  const int tid = threadIdx.x;
  const int lane = tid & 63, w = tid >> 6;
  const int wr = w >> 1, wc = w & 1;  // 4M x 2N
  const int l15 = lane & 15, l4 = lane >> 4;
  const int gx = gridDim.x;
  const int flat = blockIdx.x + blockIdx.y * gx;
  int bmi, bni;
  xcd_map(flat, &bmi, &bni);
  const size_t bm = bmi, bn = bni;
  const bf16* Ab = A + bm * 128 * (size_t)K;
  const bf16* Bb = Bt + bn * 128 * (size_t)K;

  const f32x4 zero4 = {0.f, 0.f, 0.f, 0.f};
  f32x4 acc[2][4];
  for (int m = 0; m < 2; ++m)
    for (int n = 0; n < 4; ++n) acc[m][n] = zero4;

  const int srow = tid >> 3;                 // 0..63
  const int gck = ((tid & 7) ^ (srow & 7)) * 8;
  auto stage = [&](int buf, int t) {
    const int kt = t * 64;
    bf16* la = As[buf] + tid * 8;
    bf16* lb = Bs[buf] + tid * 8;
    gl16(Ab + (size_t)srow * K + kt + gck, la);
    gl16(Ab + (size_t)(srow + 64) * K + kt + gck, la + 4096);
    gl16(Bb + (size_t)srow * K + kt + gck, lb);
    gl16(Bb + (size_t)(srow + 64) * K + kt + gck, lb + 4096);
  };
  const int xr = l15 & 7;
  const int c0 = (l4 ^ xr) * 8, c1 = ((4 + l4) ^ xr) * 8;
  auto compute = [&](int buf) {
    bf16x8 af[2][2], bfr[4][2];
    for (int m = 0; m < 2; ++m) {
      const int ro = (wr * 32 + m * 16 + l15) * 64;
      af[m][0] = *(const bf16x8*)&As[buf][ro + c0];
      af[m][1] = *(const bf16x8*)&As[buf][ro + c1];
    }
    for (int n = 0; n < 4; ++n) {
      const int ro = (wc * 64 + n * 16 + l15) * 64;
      bfr[n][0] = *(const bf16x8*)&Bs[buf][ro + c0];
      bfr[n][1] = *(const bf16x8*)&Bs[buf][ro + c1];
    }
    PRIO(1);
    for (int m = 0; m < 2; ++m)
      for (int n = 0; n < 4; ++n) {
        acc[m][n] = MFMA16(af[m][0], bfr[n][0], acc[m][n]);
        acc[m][n] = MFMA16(af[m][1], bfr[n][1], acc[m][n]);
      }
    PRIO(0);
  };

  const int nt = K >> 6;
  stage(0, 0);
  stage(1, 1);
  int cur = 0;
  for (int t = 0; t < nt - 2; ++t) {
    asm volatile("s_waitcnt vmcnt(4)" ::: "memory");
    SBAR(); SCHED0();
    compute(cur);
    SCHED0(); SBAR(); SCHED0();
    stage(cur, t + 2);
    cur ^= 1;
  }
  asm volatile("s_waitcnt vmcnt(4)" ::: "memory");
  SBAR(); SCHED0();
  compute(cur);
  cur ^= 1;
  asm volatile("s_waitcnt vmcnt(0)" ::: "memory");
  SBAR(); SCHED0();
  compute(cur);

  for (int m = 0; m < 2; ++m) {
    const int row0 = (int)bm * 128 + wr * 32 + m * 16 + l4 * 4;
    for (int n = 0; n < 4; ++n) {
      const int col = (int)bn * 128 + wc * 64 + n * 16 + l15;
      const float bv = bias[col];
      for (int r = 0; r < 4; ++r) {
        const int row = row0 + r;
        const float v = acc[m][n][r] + bv;
        const float gl = 0.5f * v * (1.0f + erff(v * 0.70710678118f));
        ((bf16*)o0)[(size_t)row * N + col] = (bf16)gl;
      }
    }
  }
}

// ---------------------------------------------------------------------------
// Fused QKV(N=3072) + cross-KV(N=2048), same 8-wave 128x128 structure,
// L2 supertile map. Grid (40, 32).
// ---------------------------------------------------------------------------
__global__ __launch_bounds__(512) void gemmqkv_k(const bf16* __restrict__ Aln,
                                                 const bf16* __restrict__ Axe,
                                                 const bf16* __restrict__ wtq,
                                                 const bf16* __restrict__ wtkv,
                                                 const float* __restrict__ bq3,
                                                 const float* __restrict__ bkv2,
                                                 bf16* __restrict__ Qb,
                                                 bf16* __restrict__ Kb1,
                                                 bf16* __restrict__ Vp1,
                                                 bf16* __restrict__ Kb2,
                                                 bf16* __restrict__ Vp2) {
  const int K = 1024;
  __shared__ bf16 As[2][128 * 64];
  __shared__ bf16 Bs[2][128 * 64];
  const int tid = threadIdx.x;
  const int lane = tid & 63, w = tid >> 6;
  const int wr = w >> 1, wc = w & 1;
  const int l15 = lane & 15, l4 = lane >> 4;
  const int flat = blockIdx.x + blockIdx.y * 40;
  int bmi, bni;
  xcd_map(flat, &bmi, &bni);
  const size_t bm = bmi, bn = bni;
  const bool qkv = bn < 24;
  const bf16* Ab = (qkv ? Aln : Axe) + bm * 128 * (size_t)K;
  const bf16* Bb = qkv ? (wtq + bn * 128 * (size_t)K)
                       : (wtkv + (bn - 24) * 128 * (size_t)K);

  const f32x4 zero4 = {0.f, 0.f, 0.f, 0.f};
  f32x4 acc[2][4];
  for (int m = 0; m < 2; ++m)
    for (int n = 0; n < 4; ++n) acc[m][n] = zero4;

  const int srow = tid >> 3;
  const int gck = ((tid & 7) ^ (srow & 7)) * 8;
  auto stage = [&](int buf, int t) {
    const int kt = t * 64;
    bf16* la = As[buf] + tid * 8;
    bf16* lb = Bs[buf] + tid * 8;
    gl16(Ab + (size_t)srow * K + kt + gck, la);
    gl16(Ab + (size_t)(srow + 64) * K + kt + gck, la + 4096);
    gl16(Bb + (size_t)srow * K + kt + gck, lb);
    gl16(Bb + (size_t)(srow + 64) * K + kt + gck, lb + 4096);
  };
  const int xr = l15 & 7;
  const int c0 = (l4 ^ xr) * 8, c1 = ((4 + l4) ^ xr) * 8;
  auto compute = [&](int buf) {
    bf16x8 af[2][2], bfr[4][2];
    for (int m = 0; m < 2; ++m) {
      const int ro = (wr * 32 + m * 16 + l15) * 64;
      af[m][0] = *(const bf16x8*)&As[buf][ro + c0];
      af[m][1] = *(const bf16x8*)&As[buf][ro + c1];
    }
    for (int n = 0; n < 4; ++n) {
      const int ro = (wc * 64 + n * 16 + l15) * 64;
      bfr[n][0] = *(const bf16x8*)&Bs[buf][ro + c0];
      bfr[n][1] = *(const bf16x8*)&Bs[buf][ro + c1];
    }
    PRIO(1);
    for (int m = 0; m < 2; ++m)
      for (int n = 0; n < 4; ++n) {
        acc[m][n] = MFMA16(af[m][0], bfr[n][0], acc[m][n]);
        acc[m][n] = MFMA16(af[m][1], bfr[n][1], acc[m][n]);
      }
    PRIO(0);
  };

  const int nt = K >> 6;
  stage(0, 0);
  stage(1, 1);
  int cur = 0;
  for (int t = 0; t < nt - 2; ++t) {
    asm volatile("s_waitcnt vmcnt(4)" ::: "memory");
    SBAR(); SCHED0();
    compute(cur);
    SCHED0(); SBAR(); SCHED0();
    stage(cur, t + 2);
    cur ^= 1;
  }
  asm volatile("s_waitcnt vmcnt(4)" ::: "memory");
  SBAR(); SCHED0();
  compute(cur);
  cur ^= 1;
  asm volatile("s_waitcnt vmcnt(0)" ::: "memory");
  SBAR(); SCHED0();
  compute(cur);

  for (int m = 0; m < 2; ++m) {
    const int row0 = (int)bm * 128 + wr * 32 + m * 16 + l4 * 4;
    for (int n = 0; n < 4; ++n) {
      const int coln = (qkv ? (int)bn : (int)bn - 24) * 128 + wc * 64 + n * 16 + l15;
      const float bv = qkv ? bq3[coln] : bkv2[coln];
      const int which = coln >> 10, c = coln & 1023;
      bf16* op = qkv ? (which == 0 ? Qb : (which == 1 ? Kb1 : Vp1))
                     : (which == 0 ? Kb2 : Vp2);
      for (int r = 0; r < 4; ++r) {
        const int row = row0 + r;
        op[(size_t)row * 1024 + c] = (bf16)(acc[m][n][r] + bv);
      }
    }
  }
}

// ---------------------------------------------------------------------------
// GEMM 128x64, BK=64, 512 thr = 8 waves (each 16x64 out), depth-2 counted
// vmcnt(3) dbuf, L2 supertile map. EPI: 0 bias->bf16 | 2 +res(f32)->bf16 |
// 4 +res(bf16)->bf16 | 5 +res(bf16)->fp32
// ---------------------------------------------------------------------------
template <int EPI>
__global__ __launch_bounds__(512) void gemm64_k(const bf16* __restrict__ A,
                                                const bf16* __restrict__ Bt,
                                                const float* __restrict__ bias,
                                                const void* __restrict__ res,
                                                void* __restrict__ o0,
                                                int K, int N) {
  __shared__ bf16 As[2][128 * 64];
  __shared__ bf16 Bs[2][64 * 64];
  const int tid = threadIdx.x;
  const int lane = tid & 63, w = tid >> 6;
  const int l15 = lane & 15, l4 = lane >> 4;
  const int gx = gridDim.x;
  const int flat = blockIdx.x + blockIdx.y * gx;
  int bmi, bni;
  xcd_map(flat, &bmi, &bni);
  const size_t bm = bmi, bn = bni;
  const bf16* Ab = A + bm * 128 * (size_t)K;
  const bf16* Bb = Bt + bn * 64 * (size_t)K;

  const f32x4 zero4 = {0.f, 0.f, 0.f, 0.f};
  f32x4 acc[4];
  for (int n = 0; n < 4; ++n) acc[n] = zero4;

  const int srow = tid >> 3;
  const int gck = ((tid & 7) ^ (srow & 7)) * 8;
  auto stage = [&](int buf, int t) {
    const int kt = t * 64;
    bf16* la = As[buf] + tid * 8;
    gl16(Ab + (size_t)srow * K + kt + gck, la);
    gl16(Ab + (size_t)(srow + 64) * K + kt + gck, la + 4096);
    gl16(Bb + (size_t)srow * K + kt + gck, Bs[buf] + tid * 8);
  };
  const int xr = l15 & 7;
  const int c0 = (l4 ^ xr) * 8, c1 = ((4 + l4) ^ xr) * 8;
  auto compute = [&](int buf) {
    bf16x8 af[2], bfr[4][2];
    {
      const int ro = (w * 16 + l15) * 64;
      af[0] = *(const bf16x8*)&As[buf][ro + c0];
      af[1] = *(const bf16x8*)&As[buf][ro + c1];
    }
    for (int n = 0; n < 4; ++n) {
      const int ro = (n * 16 + l15) * 64;
      bfr[n][0] = *(const bf16x8*)&Bs[buf][ro + c0];
      bfr[n][1] = *(const bf16x8*)&Bs[buf][ro + c1];
    }
    PRIO(1);
    for (int n = 0; n < 4; ++n) {
      acc[n] = MFMA16(af[0], bfr[n][0], acc[n]);
      acc[n] = MFMA16(af[1], bfr[n][1], acc[n]);
    }
    PRIO(0);
  };

  const int nt = K >> 6;
  stage(0, 0);
  stage(1, 1);
  int cur = 0;
  for (int t = 0; t < nt - 2; ++t) {
    asm volatile("s_waitcnt vmcnt(3)" ::: "memory");
    SBAR(); SCHED0();
    compute(cur);
    SCHED0(); SBAR(); SCHED0();
    stage(cur, t + 2);
    cur ^= 1;
  }
  asm volatile("s_waitcnt vmcnt(3)" ::: "memory");
  SBAR(); SCHED0();
  compute(cur);
  cur ^= 1;
  asm volatile("s_waitcnt vmcnt(0)" ::: "memory");
  SBAR(); SCHED0();
  compute(cur);

  const int row0 = (int)bm * 128 + w * 16 + l4 * 4;
  for (int n = 0; n < 4; ++n) {
    const int col = (int)bn * 64 + n * 16 + l15;
    const float bv = bias[col];
    for (int r = 0; r < 4; ++r) {
      const int row = row0 + r;
      const size_t idx = (size_t)row * N + col;
      float v = acc[n][r] + bv;
      if constexpr (EPI == 0) {
        ((bf16*)o0)[idx] = (bf16)v;
      } else if constexpr (EPI == 2) {
        v += ((const float*)res)[idx];
        ((bf16*)o0)[idx] = (bf16)v;
      } else if constexpr (EPI == 4) {
        v += (float)((const bf16*)res)[idx];
        ((bf16*)o0)[idx] = (bf16)v;
      } else {
        v += (float)((const bf16*)res)[idx];
        ((float*)o0)[idx] = v;
      }
    }
  }
}

// ---------------------------------------------------------------------------
// Causal flash attention with cooperative LDS K/V staging (unchanged).
// ---------------------------------------------------------------------------
__global__ __launch_bounds__(512) void attn_k(const bf16* __restrict__ Q,
                                              const bf16* __restrict__ Kb,
                                              const bf16* __restrict__ Vt,
                                              bf16* __restrict__ O) {
  __shared__ bf16 Ks[2][64 * 64];
  __shared__ bf16 Vs[2][64 * 64];
  __shared__ bf16 Plds[8][16][72];
  const int bx = blockIdx.x, bh = blockIdx.y;
  const int b = bh >> 4, h = bh & 15;
  const int tid = threadIdx.x, lane = tid & 63, w = tid >> 6;
  const int myqt = (w < 4) ? bx : (15 - bx);
  const int qbase = myqt * 64 + (w & 3) * 16;
  const int l15 = lane & 15, l4 = lane >> 4;
  const int nt = 16 - bx;

  const bf16* Qp = Q + (size_t)(b * 1024 + qbase + l15) * 1024 + h * 64 + l4 * 8;
  bf16x8 qf0 = *(const bf16x8*)Qp;
  bf16x8 qf1 = *(const bf16x8*)(Qp + 32);
  for (int i = 0; i < 8; ++i) {
    qf0[i] = (bf16)((float)qf0[i] * 0.125f);
    qf1[i] = (bf16)((float)qf1[i] * 0.125f);
  }
  bf16x8 onesf;
  for (int i = 0; i < 8; ++i) onesf[i] = (bf16)1.0f;

  const f32x4 zero4 = {0.f, 0.f, 0.f, 0.f};
  f32x4 o[4], ol;
  float mrow[4];
  for (int d = 0; d < 4; ++d) o[d] = zero4;
  ol = zero4;
  for (int r = 0; r < 4; ++r) mrow[r] = -1e30f;

  const int qrow0 = qbase + l4 * 4;

  const int srow = tid >> 3;
  const int cg = (tid & 7) ^ (srow & 7);
  const bf16* Kg = Kb + (size_t)(b * 1024 + srow) * 1024 + h * 64 + cg * 8;
  const bf16* Vg = Vt + (size_t)(bh * 64 + srow) * 1024 + cg * 8;
  auto stage = [&](int buf, int t) {
    gl16(Kg + (size_t)t * 64 * 1024, Ks[buf] + tid * 8);
    gl16(Vg + t * 64, Vs[buf] + tid * 8);
  };

  const int xr = l15 & 7;
  const int fc0 = (l4 ^ xr) * 8, fc1 = ((4 + l4) ^ xr) * 8;

  auto compute = [&](int buf, int kt) {
    const int kbase = kt * 64;
    f32x4 s[4];
    for (int n = 0; n < 4; ++n) s[n] = zero4;
    PRIO(1);
    for (int n = 0; n < 4; ++n) {
      const int ro = (n * 16 + l15) * 64;
      const bf16x8 kf0 = *(const bf16x8*)&Ks[buf][ro + fc0];
      const bf16x8 kf1 = *(const bf16x8*)&Ks[buf][ro + fc1];
      s[n] = MFMA16(qf0, kf0, s[n]);
      s[n] = MFMA16(qf1, kf1, s[n]);
    }
    PRIO(0);
    if (kt == myqt) {
      for (int n = 0; n < 4; ++n) {
        const int kc = kbase + n * 16 + l15;
        for (int r = 0; r < 4; ++r)
          if (kc > qrow0 + r) s[n][r] = -1e30f;
      }
    }
    float mx[4];
    for (int r = 0; r < 4; ++r)
      mx[r] = fmaxf(fmaxf(s[0][r], s[1][r]), fmaxf(s[2][r], s[3][r]));
    for (int d0 = 1; d0 < 16; d0 <<= 1)
      for (int r = 0; r < 4; ++r) mx[r] = fmaxf(mx[r], __shfl_xor(mx[r], d0));
    float alpha[4];
    for (int r = 0; r < 4; ++r) {
      const float mnew = fmaxf(mrow[r], mx[r]);
      alpha[r] = __expf(mrow[r] - mnew);
      mrow[r] = mnew;
    }
    for (int n = 0; n < 4; ++n)
      for (int r = 0; r < 4; ++r) s[n][r] = __expf(s[n][r] - mrow[r]);
    for (int d = 0; d < 4; ++d)
      for (int r = 0; r < 4; ++r) o[d][r] *= alpha[r];
    for (int r = 0; r < 4; ++r) ol[r] *= alpha[r];

    LGKM_FENCE();
    for (int r = 0; r < 4; ++r)
      for (int n = 0; n < 4; ++n)
        Plds[w][l4 * 4 + r][n * 16 + l15] = (bf16)s[n][r];
    LGKM_FENCE();
    const bf16x8 pf0 = *(const bf16x8*)&Plds[w][l15][l4 * 8];
    const bf16x8 pf1 = *(const bf16x8*)&Plds[w][l15][32 + l4 * 8];

    PRIO(1);
    for (int d = 0; d < 4; ++d) {
      const int ro = (d * 16 + l15) * 64;
      const bf16x8 vf0 = *(const bf16x8*)&Vs[buf][ro + fc0];
      const bf16x8 vf1 = *(const bf16x8*)&Vs[buf][ro + fc1];
      o[d] = MFMA16(pf0, vf0, o[d]);
      o[d] = MFMA16(pf1, vf1, o[d]);
    }
    ol = MFMA16(pf0, onesf, ol);
    ol = MFMA16(pf1, onesf, ol);
    PRIO(0);
  };

  stage(0, 0);
  stage(1, 1);
  int cur = 0;
  for (int t = 0; t < nt - 2; ++t) {
    asm volatile("s_waitcnt vmcnt(2)" ::: "memory");
    SBAR(); SCHED0();
    if (t <= myqt) compute(cur, t);
    SCHED0(); SBAR(); SCHED0();
    stage(cur, t + 2);
    cur ^= 1;
  }
  asm volatile("s_waitcnt vmcnt(2)" ::: "memory");
  SBAR(); SCHED0();
  if (nt - 2 <= myqt) compute(cur, nt - 2);
  cur ^= 1;
  asm volatile("s_waitcnt vmcnt(0)" ::: "memory");
  SBAR(); SCHED0();
  if (nt - 1 <= myqt) compute(cur, nt - 1);

  for (int r = 0; r < 4; ++r) {
    const float inv = 1.0f / ol[r];
    for (int d = 0; d < 4; ++d) {
      O[(size_t)(b * 1024 + qbase + l4 * 4 + r) * 1024 + h * 64 + d * 16 + l15] =
          (bf16)(o[d][r] * inv);
    }
  }
}

// ---------------------------------------------------------------------------
extern "C" void kernel_launch(void* const* d_in, const int* in_sizes, int n_in,
                              void* d_out, int out_size, void* d_ws, size_t ws_size,
                              hipStream_t stream) {
  const float* x_enc = (const float*)d_in[0];
  const float* x     = (const float*)d_in[1];
  const float* ln1_g = (const float*)d_in[2];
  const float* ln1_b = (const float*)d_in[3];
  const float* ln2_g = (const float*)d_in[4];
  const float* ln2_b = (const float*)d_in[5];
  const float* sa_wq = (const float*)d_in[6];  const float* sa_bq = (const float*)d_in[7];
  const float* sa_wk = (const float*)d_in[8];  const float* sa_bk = (const float*)d_in[9];
  const float* sa_wv = (const float*)d_in[10]; const float* sa_bv = (const float*)d_in[11];
  const float* sa_wo = (const float*)d_in[12]; const float* sa_bo = (const float*)d_in[13];
  const float* ca_wq = (const float*)d_in[14]; const float* ca_bq = (const float*)d_in[15];
  const float* ca_wk = (const float*)d_in[16]; const float* ca_bk = (const float*)d_in[17];
  const float* ca_wv = (const float*)d_in[18]; const float* ca_bv = (const float*)d_in[19];
  const float* ca_wo = (const float*)d_in[20]; const float* ca_bo = (const float*)d_in[21];
  const float* mlp_w1 = (const float*)d_in[22]; const float* mlp_b1 = (const float*)d_in[23];
  const float* mlp_w2 = (const float*)d_in[24]; const float* mlp_b2 = (const float*)d_in[25];

  char* ws = (char*)d_ws;
  size_t off = 0;
  auto take = [&](size_t bytes) { char* p = ws + off; off += (bytes + 255) & ~(size_t)255; return p; };

  bf16* wt8 = (bf16*)take((size_t)8 * 1024 * 1024 * 2);
  bf16* w1t   = (bf16*)take((size_t)4096 * 1024 * 2);
  bf16* w2t   = (bf16*)take((size_t)1024 * 4096 * 2);
  bf16* lnbuf = (bf16*)take((size_t)4096 * 1024 * 2);
  bf16* xe_bf = (bf16*)take((size_t)4096 * 1024 * 2);
  bf16* Qb    = (bf16*)take((size_t)4096 * 1024 * 2);
  bf16* Kb1   = (bf16*)take((size_t)4096 * 1024 * 2);
  bf16* Vp1   = (bf16*)take((size_t)4096 * 1024 * 2);
  bf16* Vt1   = (bf16*)take((size_t)4096 * 1024 * 2);
  bf16* Kb2   = (bf16*)take((size_t)4096 * 1024 * 2);
  bf16* Vp2   = (bf16*)take((size_t)4096 * 1024 * 2);
  bf16* Vt2   = (bf16*)take((size_t)4096 * 1024 * 2);
  bf16* AOb   = (bf16*)take((size_t)4096 * 1024 * 2);
  bf16* x1    = (bf16*)take((size_t)4096 * 1024 * 2);
  bf16* x2    = (bf16*)take((size_t)4096 * 1024 * 2);
  bf16* Hb    = (bf16*)take((size_t)4096 * 4096 * 2);
  float* bq3  = (float*)take((size_t)3072 * 4);
  float* bkv2 = (float*)take((size_t)2048 * 4);

  bf16* wt[8];
  for (int i = 0; i < 8; ++i) wt[i] = wt8 + (size_t)i * 1024 * 1024;

  const dim3 blk(256);
  PrepArgs pa;
  pa.wsq[0] = sa_wq; pa.wsq[1] = sa_wk; pa.wsq[2] = sa_wv; pa.wsq[3] = sa_wo;
  pa.wsq[4] = ca_wq; pa.wsq[5] = ca_wk; pa.wsq[6] = ca_wv; pa.wsq[7] = ca_wo;
  pa.w1 = mlp_w1; pa.w2 = mlp_w2; pa.xe = x_enc;
  pa.bs[0] = sa_bq; pa.bs[1] = sa_bk; pa.bs[2] = sa_bv;
  pa.bs[3] = ca_bk; pa.bs[4] = ca_bv;
  pa.wt8 = wt8; pa.w1t = w1t; pa.w2t = w2t; pa.xebf = xe_bf;
  pa.bq3 = bq3; pa.bkv2 = bkv2;
  prep_k<<<20485, blk, 0, stream>>>(pa);

  // ln1(x); fused [self QKV | cross KV]; both V transposes
  ln_k<float><<<4096, blk, 0, stream>>>(x, ln1_g, ln1_b, lnbuf);
  gemmqkv_k<<<dim3(40, 32), dim3(512), 0, stream>>>(lnbuf, xe_bf, wt[0], wt[5],
                                                    bq3, bkv2, Qb, Kb1, Vp1, Kb2, Vp2);
  vtrans_k<<<dim3(16, 64, 2), dim3(512), 0, stream>>>(Vp1, Vp2, Vt1, Vt2);

  // x1 = x + SelfAttn
  attn_k<<<dim3(8, 64), dim3(512), 0, stream>>>(Qb, Kb1, Vt1, AOb);
  gemm64_k<2><<<dim3(16, 32), dim3(512), 0, stream>>>(AOb, wt[3], sa_bo, x, x1, 1024, 1024);

  // x2 = x1 + CrossAttn(ln1(x1), x_encoder)
  ln_k<bf16><<<4096, blk, 0, stream>>>(x1, ln1_g, ln1_b, lnbuf);
  gemm64_k<0><<<dim3(16, 32), dim3(512), 0, stream>>>(lnbuf, wt[4], ca_bq, nullptr, Qb, 1024, 1024);
  attn_k<<<dim3(8, 64), dim3(512), 0, stream>>>(Qb, Kb2, Vt2, AOb);
  gemm64_k<4><<<dim3(16, 32), dim3(512), 0, stream>>>(AOb, wt[7], ca_bo, x1, x2, 1024, 1024);

  // out = x2 + MLP(ln2(x2))
  ln_k<bf16><<<4096, blk, 0, stream>>>(x2, ln2_g, ln2_b, lnbuf);
  gemm_k<3><<<dim3(32, 32), dim3(512), 0, stream>>>(lnbuf, w1t, mlp_b1, Hb, 1024, 4096);
  gemm64_k<5><<<dim3(16, 32), dim3(512), 0, stream>>>(Hb, w2t, mlp_b2, x2,
                                                      (float*)d_out, 4096, 1024);

  (void)in_sizes; (void)n_in; (void)out_size; (void)ws_size;
}

// Round 19
// 296.568 us; speedup vs baseline: 1.0740x; 1.0282x over previous
//
#include <hip/hip_runtime.h>
#include <hip/hip_bf16.h>

typedef __bf16 bf16;
typedef __attribute__((ext_vector_type(4))) __bf16 bf16x4;
typedef __attribute__((ext_vector_type(8))) __bf16 bf16x8;
typedef __attribute__((ext_vector_type(4))) float f32x4;

#define MFMA16(a, b, c) __builtin_amdgcn_mfma_f32_16x16x32_bf16(a, b, c, 0, 0, 0)

#define LGKM_FENCE()                                      \
  do {                                                    \
    asm volatile("s_waitcnt lgkmcnt(0)" ::: "memory");    \
    __builtin_amdgcn_sched_barrier(0);                    \
  } while (0)

#define SCHED0() __builtin_amdgcn_sched_barrier(0)
#define SBAR() __builtin_amdgcn_s_barrier()
#define PRIO(x) __builtin_amdgcn_s_setprio(x)

typedef __attribute__((address_space(1))) void gvoid;
typedef __attribute__((address_space(3))) void lvoid;
__device__ __forceinline__ void gl16(const bf16* g, bf16* l) {
  __builtin_amdgcn_global_load_lds((gvoid*)g, (lvoid*)l, 16, 0, 0);
}

// L2-aware XCD supertile (R18-proven: MLP1 FETCH 80->41MB, +10.6us total).
// Requires gy == 32 and nwg/(8*gx) == 4. Each XCD walks 4x4 supertiles:
// working set 4 A-panels + 4 B-panels = 2MB < 4MB L2.
__device__ __forceinline__ void xcd_map(int flat, int* bm, int* bn) {
  const int xcd = flat & 7, local = flat >> 3;
  const int sup = local >> 4, s = local & 15;
  *bm = xcd * 4 + (s >> 2);
  *bn = sup * 4 + (s & 3);
}

// Problem geometry: B=4, T=1024, D=1024, H=16, HD=64, DFF=4096, M=4096

// ---------------------------------------------------------------------------
// Fused preprocessing (R13-proven): one flat-grid dispatch.
// ---------------------------------------------------------------------------
struct PrepArgs {
  const float* wsq[8];
  const float* w1;
  const float* w2;
  const float* xe;
  const float* bs[5];
  bf16* wt8;
  bf16* w1t;
  bf16* w2t;
  bf16* xebf;
  float* bq3;
  float* bkv2;
};

__global__ __launch_bounds__(256) void prep_k(PrepArgs a) {
  __shared__ float t[32][33];
  const int blk = blockIdx.x, tid = threadIdx.x;
  const int tx = tid & 31, ty = tid >> 5;
  if (blk < 8192) {
    const int z = blk >> 10, b = blk & 1023;
    const float* w = a.wsq[z];
    bf16* wt = a.wt8 + ((size_t)z << 20);
    const int nb = (b & 31) * 32, kb = (b >> 5) * 32;
    for (int i = 0; i < 4; ++i)
      t[ty + i * 8][tx] = w[(size_t)(kb + ty + i * 8) * 1024 + nb + tx];
    __syncthreads();
    for (int i = 0; i < 4; ++i)
      wt[(size_t)(nb + ty + i * 8) * 1024 + kb + tx] = (bf16)t[tx][ty + i * 8];
  } else if (blk < 12288) {
    const int b = blk - 8192;
    const int nb = (b & 127) * 32, kb = (b >> 7) * 32;
    for (int i = 0; i < 4; ++i)
      t[ty + i * 8][tx] = a.w1[(size_t)(kb + ty + i * 8) * 4096 + nb + tx];
    __syncthreads();
    for (int i = 0; i < 4; ++i)
      a.w1t[(size_t)(nb + ty + i * 8) * 1024 + kb + tx] = (bf16)t[tx][ty + i * 8];
  } else if (blk < 16384) {
    const int b = blk - 12288;
    const int nb = (b & 31) * 32, kb = (b >> 5) * 32;
    for (int i = 0; i < 4; ++i)
      t[ty + i * 8][tx] = a.w2[(size_t)(kb + ty + i * 8) * 1024 + nb + tx];
    __syncthreads();
    for (int i = 0; i < 4; ++i)
      a.w2t[(size_t)(nb + ty + i * 8) * 4096 + kb + tx] = (bf16)t[tx][ty + i * 8];
  } else if (blk < 20480) {
    const int i = (blk - 16384) * 256 + tid;
    const float4 v = ((const float4*)a.xe)[i];
    bf16* o = a.xebf + (size_t)i * 4;
    o[0] = (bf16)v.x; o[1] = (bf16)v.y; o[2] = (bf16)v.z; o[3] = (bf16)v.w;
  } else {
    const int i = blk - 20480;
    float* d = (i < 3) ? a.bq3 + i * 1024 : a.bkv2 + (i - 3) * 1024;
    ((float4*)d)[tid] = ((const float4*)a.bs[i])[tid];
  }
}

// ---------------------------------------------------------------------------
// V transpose x2: Vp[M,1024] (head cols) -> Vt[B*H][64][1024].
// ---------------------------------------------------------------------------
__global__ __launch_bounds__(512) void vtrans_k(const bf16* __restrict__ V0,
                                                const bf16* __restrict__ V1,
                                                bf16* __restrict__ T0,
                                                bf16* __restrict__ T1) {
  const bf16* Vp = blockIdx.z ? V1 : V0;
  bf16* Vt = blockIdx.z ? T1 : T0;
  __shared__ bf16 tl[64][72];
  const int tt = blockIdx.x, bh = blockIdx.y;
  const int b = bh >> 4, h = bh & 15;
  const int tid = threadIdx.x;
  const int row = tid >> 3, ck = tid & 7;
  *(bf16x8*)&tl[row][ck * 8] =
      *(const bf16x8*)&Vp[(size_t)(b * 1024 + tt * 64 + row) * 1024 + h * 64 + ck * 8];
  __syncthreads();
  const int hd = tid >> 3, tc = tid & 7;
  bf16 tmp[8];
#pragma unroll
  for (int e = 0; e < 8; ++e) tmp[e] = tl[tc * 8 + e][hd];
  *(bf16x8*)&Vt[(size_t)(bh * 64 + hd) * 1024 + tt * 64 + tc * 8] = *(bf16x8*)tmp;
}

// ---------------------------------------------------------------------------
// LayerNorm over D=1024. TIN = float or bf16.
// ---------------------------------------------------------------------------
template <typename TIN>
__global__ __launch_bounds__(256) void ln_k(const TIN* __restrict__ x,
                                            const float* __restrict__ g,
                                            const float* __restrict__ bta,
                                            bf16* __restrict__ out) {
  const int row = blockIdx.x, tid = threadIdx.x;
  float v0, v1, v2, v3;
  if constexpr (sizeof(TIN) == 4) {
    const float4 v = ((const float4*)((const float*)x + (size_t)row * 1024))[tid];
    v0 = v.x; v1 = v.y; v2 = v.z; v3 = v.w;
  } else {
    const bf16x4 v = *(const bf16x4*)((const bf16*)x + (size_t)row * 1024 + tid * 4);
    v0 = (float)v[0]; v1 = (float)v[1]; v2 = (float)v[2]; v3 = (float)v[3];
  }
  float s = v0 + v1 + v2 + v3;
  float sq = v0 * v0 + v1 * v1 + v2 * v2 + v3 * v3;
  for (int d = 1; d < 64; d <<= 1) { s += __shfl_xor(s, d); sq += __shfl_xor(sq, d); }
  __shared__ float rs[4], rq[4];
  const int w = tid >> 6, lane = tid & 63;
  if (lane == 0) { rs[w] = s; rq[w] = sq; }
  __syncthreads();
  s = rs[0] + rs[1] + rs[2] + rs[3];
  sq = rq[0] + rq[1] + rq[2] + rq[3];
  const float mean = s * (1.0f / 1024.0f);
  const float var = sq * (1.0f / 1024.0f) - mean * mean;
  const float rstd = rsqrtf(var + 1e-5f);
  const float4 gv = ((const float4*)g)[tid];
  const float4 bv = ((const float4*)bta)[tid];
  bf16* o = out + (size_t)row * 1024 + tid * 4;
  o[0] = (bf16)((v0 - mean) * rstd * gv.x + bv.x);
  o[1] = (bf16)((v1 - mean) * rstd * gv.y + bv.y);
  o[2] = (bf16)((v2 - mean) * rstd * gv.z + bv.z);
  o[3] = (bf16)((v3 - mean) * rstd * gv.w + bv.w);
}

// ---------------------------------------------------------------------------
// GEMM 128x128, BK=64, 512 thr = 8 waves (4M x 2N, 32x64 out each),
// depth-2 counted-vmcnt dbuf, XOR-swizzled LDS, L2 supertile map.
// EPI: 3 = bias + exact GELU -> bf16 (MLP1). (R18-proven best)
// ---------------------------------------------------------------------------
template <int EPI>
__global__ __launch_bounds__(512) void gemm_k(const bf16* __restrict__ A,
                                              const bf16* __restrict__ Bt,
                                              const float* __restrict__ bias,
                                              void* __restrict__ o0,
                                              int K, int N) {
  __shared__ bf16 As[2][128 * 64];
  __shared__ bf16 Bs[2][128 * 64];
  const int tid = threadIdx.x;
  const int lane = tid & 63, w = tid >> 6;
  const int wr = w >> 1, wc = w & 1;  // 4M x 2N
  const int l15 = lane & 15, l4 = lane >> 4;
  const int gx = gridDim.x;
  const int flat = blockIdx.x + blockIdx.y * gx;
  int bmi, bni;
  xcd_map(flat, &bmi, &bni);
  const size_t bm = bmi, bn = bni;
  const bf16* Ab = A + bm * 128 * (size_t)K;
  const bf16* Bb = Bt + bn * 128 * (size_t)K;

  const f32x4 zero4 = {0.f, 0.f, 0.f, 0.f};
  f32x4 acc[2][4];
  for (int m = 0; m < 2; ++m)
    for (int n = 0; n < 4; ++n) acc[m][n] = zero4;

  const int srow = tid >> 3;                 // 0..63
  const int gck = ((tid & 7) ^ (srow & 7)) * 8;
  auto stage = [&](int buf, int t) {
    const int kt = t * 64;
    bf16* la = As[buf] + tid * 8;
    bf16* lb = Bs[buf] + tid * 8;
    gl16(Ab + (size_t)srow * K + kt + gck, la);
    gl16(Ab + (size_t)(srow + 64) * K + kt + gck, la + 4096);
    gl16(Bb + (size_t)srow * K + kt + gck, lb);
    gl16(Bb + (size_t)(srow + 64) * K + kt + gck, lb + 4096);
  };
  const int xr = l15 & 7;
  const int c0 = (l4 ^ xr) * 8, c1 = ((4 + l4) ^ xr) * 8;
  auto compute = [&](int buf) {
    bf16x8 af[2][2], bfr[4][2];
    for (int m = 0; m < 2; ++m) {
      const int ro = (wr * 32 + m * 16 + l15) * 64;
      af[m][0] = *(const bf16x8*)&As[buf][ro + c0];
      af[m][1] = *(const bf16x8*)&As[buf][ro + c1];
    }
    for (int n = 0; n < 4; ++n) {
      const int ro = (wc * 64 + n * 16 + l15) * 64;
      bfr[n][0] = *(const bf16x8*)&Bs[buf][ro + c0];
      bfr[n][1] = *(const bf16x8*)&Bs[buf][ro + c1];
    }
    PRIO(1);
    for (int m = 0; m < 2; ++m)
      for (int n = 0; n < 4; ++n) {
        acc[m][n] = MFMA16(af[m][0], bfr[n][0], acc[m][n]);
        acc[m][n] = MFMA16(af[m][1], bfr[n][1], acc[m][n]);
      }
    PRIO(0);
  };

  const int nt = K >> 6;
  stage(0, 0);
  stage(1, 1);
  int cur = 0;
  for (int t = 0; t < nt - 2; ++t) {
    asm volatile("s_waitcnt vmcnt(4)" ::: "memory");
    SBAR(); SCHED0();
    compute(cur);
    SCHED0(); SBAR(); SCHED0();
    stage(cur, t + 2);
    cur ^= 1;
  }
  asm volatile("s_waitcnt vmcnt(4)" ::: "memory");
  SBAR(); SCHED0();
  compute(cur);
  cur ^= 1;
  asm volatile("s_waitcnt vmcnt(0)" ::: "memory");
  SBAR(); SCHED0();
  compute(cur);

  for (int m = 0; m < 2; ++m) {
    const int row0 = (int)bm * 128 + wr * 32 + m * 16 + l4 * 4;
    for (int n = 0; n < 4; ++n) {
      const int col = (int)bn * 128 + wc * 64 + n * 16 + l15;
      const float bv = bias[col];
      for (int r = 0; r < 4; ++r) {
        const int row = row0 + r;
        const float v = acc[m][n][r] + bv;
        const float gl = 0.5f * v * (1.0f + erff(v * 0.70710678118f));
        ((bf16*)o0)[(size_t)row * N + col] = (bf16)gl;
      }
    }
  }
}

// ---------------------------------------------------------------------------
// Fused QKV(N=3072) + cross-KV(N=2048), same 8-wave 128x128 structure,
// L2 supertile map. Grid (40, 32).
// ---------------------------------------------------------------------------
__global__ __launch_bounds__(512) void gemmqkv_k(const bf16* __restrict__ Aln,
                                                 const bf16* __restrict__ Axe,
                                                 const bf16* __restrict__ wtq,
                                                 const bf16* __restrict__ wtkv,
                                                 const float* __restrict__ bq3,
                                                 const float* __restrict__ bkv2,
                                                 bf16* __restrict__ Qb,
                                                 bf16* __restrict__ Kb1,
                                                 bf16* __restrict__ Vp1,
                                                 bf16* __restrict__ Kb2,
                                                 bf16* __restrict__ Vp2) {
  const int K = 1024;
  __shared__ bf16 As[2][128 * 64];
  __shared__ bf16 Bs[2][128 * 64];
  const int tid = threadIdx.x;
  const int lane = tid & 63, w = tid >> 6;
  const int wr = w >> 1, wc = w & 1;
  const int l15 = lane & 15, l4 = lane >> 4;
  const int flat = blockIdx.x + blockIdx.y * 40;
  int bmi, bni;
  xcd_map(flat, &bmi, &bni);
  const size_t bm = bmi, bn = bni;
  const bool qkv = bn < 24;
  const bf16* Ab = (qkv ? Aln : Axe) + bm * 128 * (size_t)K;
  const bf16* Bb = qkv ? (wtq + bn * 128 * (size_t)K)
                       : (wtkv + (bn - 24) * 128 * (size_t)K);

  const f32x4 zero4 = {0.f, 0.f, 0.f, 0.f};
  f32x4 acc[2][4];
  for (int m = 0; m < 2; ++m)
    for (int n = 0; n < 4; ++n) acc[m][n] = zero4;

  const int srow = tid >> 3;
  const int gck = ((tid & 7) ^ (srow & 7)) * 8;
  auto stage = [&](int buf, int t) {
    const int kt = t * 64;
    bf16* la = As[buf] + tid * 8;
    bf16* lb = Bs[buf] + tid * 8;
    gl16(Ab + (size_t)srow * K + kt + gck, la);
    gl16(Ab + (size_t)(srow + 64) * K + kt + gck, la + 4096);
    gl16(Bb + (size_t)srow * K + kt + gck, lb);
    gl16(Bb + (size_t)(srow + 64) * K + kt + gck, lb + 4096);
  };
  const int xr = l15 & 7;
  const int c0 = (l4 ^ xr) * 8, c1 = ((4 + l4) ^ xr) * 8;
  auto compute = [&](int buf) {
    bf16x8 af[2][2], bfr[4][2];
    for (int m = 0; m < 2; ++m) {
      const int ro = (wr * 32 + m * 16 + l15) * 64;
      af[m][0] = *(const bf16x8*)&As[buf][ro + c0];
      af[m][1] = *(const bf16x8*)&As[buf][ro + c1];
    }
    for (int n = 0; n < 4; ++n) {
      const int ro = (wc * 64 + n * 16 + l15) * 64;
      bfr[n][0] = *(const bf16x8*)&Bs[buf][ro + c0];
      bfr[n][1] = *(const bf16x8*)&Bs[buf][ro + c1];
    }
    PRIO(1);
    for (int m = 0; m < 2; ++m)
      for (int n = 0; n < 4; ++n) {
        acc[m][n] = MFMA16(af[m][0], bfr[n][0], acc[m][n]);
        acc[m][n] = MFMA16(af[m][1], bfr[n][1], acc[m][n]);
      }
    PRIO(0);
  };

  const int nt = K >> 6;
  stage(0, 0);
  stage(1, 1);
  int cur = 0;
  for (int t = 0; t < nt - 2; ++t) {
    asm volatile("s_waitcnt vmcnt(4)" ::: "memory");
    SBAR(); SCHED0();
    compute(cur);
    SCHED0(); SBAR(); SCHED0();
    stage(cur, t + 2);
    cur ^= 1;
  }
  asm volatile("s_waitcnt vmcnt(4)" ::: "memory");
  SBAR(); SCHED0();
  compute(cur);
  cur ^= 1;
  asm volatile("s_waitcnt vmcnt(0)" ::: "memory");
  SBAR(); SCHED0();
  compute(cur);

  for (int m = 0; m < 2; ++m) {
    const int row0 = (int)bm * 128 + wr * 32 + m * 16 + l4 * 4;
    for (int n = 0; n < 4; ++n) {
      const int coln = (qkv ? (int)bn : (int)bn - 24) * 128 + wc * 64 + n * 16 + l15;
      const float bv = qkv ? bq3[coln] : bkv2[coln];
      const int which = coln >> 10, c = coln & 1023;
      bf16* op = qkv ? (which == 0 ? Qb : (which == 1 ? Kb1 : Vp1))
                     : (which == 0 ? Kb2 : Vp2);
      for (int r = 0; r < 4; ++r) {
        const int row = row0 + r;
        op[(size_t)row * 1024 + c] = (bf16)(acc[m][n][r] + bv);
      }
    }
  }
}

// ---------------------------------------------------------------------------
// GEMM 128x64, BK=64, 512 thr = 8 waves (each 16x64 out), depth-3 counted
// vmcnt(6) triple-buffer (72KB LDS, 2 blocks/CU), L2 supertile map.
// EPI: 0 bias->bf16 | 2 +res(f32)->bf16 | 4 +res(bf16)->bf16 | 5 ->fp32
// ---------------------------------------------------------------------------
template <int EPI>
__global__ __launch_bounds__(512) void gemm64_k(const bf16* __restrict__ A,
                                                const bf16* __restrict__ Bt,
                                                const float* __restrict__ bias,
                                                const void* __restrict__ res,
                                                void* __restrict__ o0,
                                                int K, int N) {
  __shared__ bf16 As[3][128 * 64];
  __shared__ bf16 Bs[3][64 * 64];
  const int tid = threadIdx.x;
  const int lane = tid & 63, w = tid >> 6;
  const int l15 = lane & 15, l4 = lane >> 4;
  const int gx = gridDim.x;
  const int flat = blockIdx.x + blockIdx.y * gx;
  int bmi, bni;
  xcd_map(flat, &bmi, &bni);
  const size_t bm = bmi, bn = bni;
  const bf16* Ab = A + bm * 128 * (size_t)K;
  const bf16* Bb = Bt + bn * 64 * (size_t)K;

  const f32x4 zero4 = {0.f, 0.f, 0.f, 0.f};
  f32x4 acc[4];
  for (int n = 0; n < 4; ++n) acc[n] = zero4;

  const int srow = tid >> 3;
  const int gck = ((tid & 7) ^ (srow & 7)) * 8;
  auto stage = [&](int buf, int t) {
    const int kt = t * 64;
    bf16* la = As[buf] + tid * 8;
    gl16(Ab + (size_t)srow * K + kt + gck, la);
    gl16(Ab + (size_t)(srow + 64) * K + kt + gck, la + 4096);
    gl16(Bb + (size_t)srow * K + kt + gck, Bs[buf] + tid * 8);
  };
  const int xr = l15 & 7;
  const int c0 = (l4 ^ xr) * 8, c1 = ((4 + l4) ^ xr) * 8;
  auto compute = [&](int buf) {
    bf16x8 af[2], bfr[4][2];
    {
      const int ro = (w * 16 + l15) * 64;
      af[0] = *(const bf16x8*)&As[buf][ro + c0];
      af[1] = *(const bf16x8*)&As[buf][ro + c1];
    }
    for (int n = 0; n < 4; ++n) {
      const int ro = (n * 16 + l15) * 64;
      bfr[n][0] = *(const bf16x8*)&Bs[buf][ro + c0];
      bfr[n][1] = *(const bf16x8*)&Bs[buf][ro + c1];
    }
    PRIO(1);
    for (int n = 0; n < 4; ++n) {
      acc[n] = MFMA16(af[0], bfr[n][0], acc[n]);
      acc[n] = MFMA16(af[1], bfr[n][1], acc[n]);
    }
    PRIO(0);
  };

  const int nt = K >> 6;  // >= 16
  stage(0, 0);
  stage(1, 1);
  stage(2, 2);
  int cur = 0;
  for (int t = 0; t < nt - 3; ++t) {
    asm volatile("s_waitcnt vmcnt(6)" ::: "memory");
    SBAR(); SCHED0();
    compute(cur);
    SCHED0(); SBAR(); SCHED0();
    stage(cur, t + 3);
    cur = (cur == 2) ? 0 : cur + 1;
  }
  asm volatile("s_waitcnt vmcnt(6)" ::: "memory");
  SBAR(); SCHED0();
  compute(cur);
  cur = (cur == 2) ? 0 : cur + 1;
  asm volatile("s_waitcnt vmcnt(3)" ::: "memory");
  SBAR(); SCHED0();
  compute(cur);
  cur = (cur == 2) ? 0 : cur + 1;
  asm volatile("s_waitcnt vmcnt(0)" ::: "memory");
  SBAR(); SCHED0();
  compute(cur);

  const int row0 = (int)bm * 128 + w * 16 + l4 * 4;
  for (int n = 0; n < 4; ++n) {
    const int col = (int)bn * 64 + n * 16 + l15;
    const float bv = bias[col];
    for (int r = 0; r < 4; ++r) {
      const int row = row0 + r;
      const size_t idx = (size_t)row * N + col;
      float v = acc[n][r] + bv;
      if constexpr (EPI == 0) {
        ((bf16*)o0)[idx] = (bf16)v;
      } else if constexpr (EPI == 2) {
        v += ((const float*)res)[idx];
        ((bf16*)o0)[idx] = (bf16)v;
      } else if constexpr (EPI == 4) {
        v += (float)((const bf16*)res)[idx];
        ((bf16*)o0)[idx] = (bf16)v;
      } else {
        v += (float)((const bf16*)res)[idx];
        ((float*)o0)[idx] = v;
      }
    }
  }
}

// ---------------------------------------------------------------------------
// Causal flash attention with cooperative LDS K/V staging.
// XCD-grouped block map: each XCD owns 8 bh's (2MB K/V working set in L2).
// ---------------------------------------------------------------------------
__global__ __launch_bounds__(512) void attn_k(const bf16* __restrict__ Q,
                                              const bf16* __restrict__ Kb,
                                              const bf16* __restrict__ Vt,
                                              bf16* __restrict__ O) {
  __shared__ bf16 Ks[2][64 * 64];
  __shared__ bf16 Vs[2][64 * 64];
  __shared__ bf16 Plds[8][16][72];
  const int flat = blockIdx.x + blockIdx.y * 8;
  const int xcd = flat & 7, j = flat >> 3;
  const int bx = j >> 3, bh = xcd * 8 + (j & 7);
  const int b = bh >> 4, h = bh & 15;
  const int tid = threadIdx.x, lane = tid & 63, w = tid >> 6;
  const int myqt = (w < 4) ? bx : (15 - bx);
  const int qbase = myqt * 64 + (w & 3) * 16;
  const int l15 = lane & 15, l4 = lane >> 4;
  const int nt = 16 - bx;

  const bf16* Qp = Q + (size_t)(b * 1024 + qbase + l15) * 1024 + h * 64 + l4 * 8;
  bf16x8 qf0 = *(const bf16x8*)Qp;
  bf16x8 qf1 = *(const bf16x8*)(Qp + 32);
  for (int i = 0; i < 8; ++i) {
    qf0[i] = (bf16)((float)qf0[i] * 0.125f);
    qf1[i] = (bf16)((float)qf1[i] * 0.125f);
  }
  bf16x8 onesf;
  for (int i = 0; i < 8; ++i) onesf[i] = (bf16)1.0f;

  const f32x4 zero4 = {0.f, 0.f, 0.f, 0.f};
  f32x4 o[4], ol;
  float mrow[4];
  for (int d = 0; d < 4; ++d) o[d] = zero4;
  ol = zero4;
  for (int r = 0; r < 4; ++r) mrow[r] = -1e30f;

  const int qrow0 = qbase + l4 * 4;

  const int srow = tid >> 3;
  const int cg = (tid & 7) ^ (srow & 7);
  const bf16* Kg = Kb + (size_t)(b * 1024 + srow) * 1024 + h * 64 + cg * 8;
  const bf16* Vg = Vt + (size_t)(bh * 64 + srow) * 1024 + cg * 8;
  auto stage = [&](int buf, int t) {
    gl16(Kg + (size_t)t * 64 * 1024, Ks[buf] + tid * 8);
    gl16(Vg + t * 64, Vs[buf] + tid * 8);
  };

  const int xr = l15 & 7;
  const int fc0 = (l4 ^ xr) * 8, fc1 = ((4 + l4) ^ xr) * 8;

  auto compute = [&](int buf, int kt) {
    const int kbase = kt * 64;
    f32x4 s[4];
    for (int n = 0; n < 4; ++n) s[n] = zero4;
    PRIO(1);
    for (int n = 0; n < 4; ++n) {
      const int ro = (n * 16 + l15) * 64;
      const bf16x8 kf0 = *(const bf16x8*)&Ks[buf][ro + fc0];
      const bf16x8 kf1 = *(const bf16x8*)&Ks[buf][ro + fc1];
      s[n] = MFMA16(qf0, kf0, s[n]);
      s[n] = MFMA16(qf1, kf1, s[n]);
    }
    PRIO(0);
    if (kt == myqt) {
      for (int n = 0; n < 4; ++n) {
        const int kc = kbase + n * 16 + l15;
        for (int r = 0; r < 4; ++r)
          if (kc > qrow0 + r) s[n][r] = -1e30f;
      }
    }
    float mx[4];
    for (int r = 0; r < 4; ++r)
      mx[r] = fmaxf(fmaxf(s[0][r], s[1][r]), fmaxf(s[2][r], s[3][r]));
    for (int d0 = 1; d0 < 16; d0 <<= 1)
      for (int r = 0; r < 4; ++r) mx[r] = fmaxf(mx[r], __shfl_xor(mx[r], d0));
    float alpha[4];
    for (int r = 0; r < 4; ++r) {
      const float mnew = fmaxf(mrow[r], mx[r]);
      alpha[r] = __expf(mrow[r] - mnew);
      mrow[r] = mnew;
    }
    for (int n = 0; n < 4; ++n)
      for (int r = 0; r < 4; ++r) s[n][r] = __expf(s[n][r] - mrow[r]);
    for (int d = 0; d < 4; ++d)
      for (int r = 0; r < 4; ++r) o[d][r] *= alpha[r];
    for (int r = 0; r < 4; ++r) ol[r] *= alpha[r];

    LGKM_FENCE();
    for (int r = 0; r < 4; ++r)
      for (int n = 0; n < 4; ++n)
        Plds[w][l4 * 4 + r][n * 16 + l15] = (bf16)s[n][r];
    LGKM_FENCE();
    const bf16x8 pf0 = *(const bf16x8*)&Plds[w][l15][l4 * 8];
    const bf16x8 pf1 = *(const bf16x8*)&Plds[w][l15][32 + l4 * 8];

    PRIO(1);
    for (int d = 0; d < 4; ++d) {
      const int ro = (d * 16 + l15) * 64;
      const bf16x8 vf0 = *(const bf16x8*)&Vs[buf][ro + fc0];
      const bf16x8 vf1 = *(const bf16x8*)&Vs[buf][ro + fc1];
      o[d] = MFMA16(pf0, vf0, o[d]);
      o[d] = MFMA16(pf1, vf1, o[d]);
    }
    ol = MFMA16(pf0, onesf, ol);
    ol = MFMA16(pf1, onesf, ol);
    PRIO(0);
  };

  stage(0, 0);
  stage(1, 1);
  int cur = 0;
  for (int t = 0; t < nt - 2; ++t) {
    asm volatile("s_waitcnt vmcnt(2)" ::: "memory");
    SBAR(); SCHED0();
    if (t <= myqt) compute(cur, t);
    SCHED0(); SBAR(); SCHED0();
    stage(cur, t + 2);
    cur ^= 1;
  }
  asm volatile("s_waitcnt vmcnt(2)" ::: "memory");
  SBAR(); SCHED0();
  if (nt - 2 <= myqt) compute(cur, nt - 2);
  cur ^= 1;
  asm volatile("s_waitcnt vmcnt(0)" ::: "memory");
  SBAR(); SCHED0();
  if (nt - 1 <= myqt) compute(cur, nt - 1);

  for (int r = 0; r < 4; ++r) {
    const float inv = 1.0f / ol[r];
    for (int d = 0; d < 4; ++d) {
      O[(size_t)(b * 1024 + qbase + l4 * 4 + r) * 1024 + h * 64 + d * 16 + l15] =
          (bf16)(o[d][r] * inv);
    }
  }
}

// ---------------------------------------------------------------------------
extern "C" void kernel_launch(void* const* d_in, const int* in_sizes, int n_in,
                              void* d_out, int out_size, void* d_ws, size_t ws_size,
                              hipStream_t stream) {
  const float* x_enc = (const float*)d_in[0];
  const float* x     = (const float*)d_in[1];
  const float* ln1_g = (const float*)d_in[2];
  const float* ln1_b = (const float*)d_in[3];
  const float* ln2_g = (const float*)d_in[4];
  const float* ln2_b = (const float*)d_in[5];
  const float* sa_wq = (const float*)d_in[6];  const float* sa_bq = (const float*)d_in[7];
  const float* sa_wk = (const float*)d_in[8];  const float* sa_bk = (const float*)d_in[9];
  const float* sa_wv = (const float*)d_in[10]; const float* sa_bv = (const float*)d_in[11];
  const float* sa_wo = (const float*)d_in[12]; const float* sa_bo = (const float*)d_in[13];
  const float* ca_wq = (const float*)d_in[14]; const float* ca_bq = (const float*)d_in[15];
  const float* ca_wk = (const float*)d_in[16]; const float* ca_bk = (const float*)d_in[17];
  const float* ca_wv = (const float*)d_in[18]; const float* ca_bv = (const float*)d_in[19];
  const float* ca_wo = (const float*)d_in[20]; const float* ca_bo = (const float*)d_in[21];
  const float* mlp_w1 = (const float*)d_in[22]; const float* mlp_b1 = (const float*)d_in[23];
  const float* mlp_w2 = (const float*)d_in[24]; const float* mlp_b2 = (const float*)d_in[25];

  char* ws = (char*)d_ws;
  size_t off = 0;
  auto take = [&](size_t bytes) { char* p = ws + off; off += (bytes + 255) & ~(size_t)255; return p; };

  bf16* wt8 = (bf16*)take((size_t)8 * 1024 * 1024 * 2);
  bf16* w1t   = (bf16*)take((size_t)4096 * 1024 * 2);
  bf16* w2t   = (bf16*)take((size_t)1024 * 4096 * 2);
  bf16* lnbuf = (bf16*)take((size_t)4096 * 1024 * 2);
  bf16* xe_bf = (bf16*)take((size_t)4096 * 1024 * 2);
  bf16* Qb    = (bf16*)take((size_t)4096 * 1024 * 2);
  bf16* Kb1   = (bf16*)take((size_t)4096 * 1024 * 2);
  bf16* Vp1   = (bf16*)take((size_t)4096 * 1024 * 2);
  bf16* Vt1   = (bf16*)take((size_t)4096 * 1024 * 2);
  bf16* Kb2   = (bf16*)take((size_t)4096 * 1024 * 2);
  bf16* Vp2   = (bf16*)take((size_t)4096 * 1024 * 2);
  bf16* Vt2   = (bf16*)take((size_t)4096 * 1024 * 2);
  bf16* AOb   = (bf16*)take((size_t)4096 * 1024 * 2);
  bf16* x1    = (bf16*)take((size_t)4096 * 1024 * 2);
  bf16* x2    = (bf16*)take((size_t)4096 * 1024 * 2);
  bf16* Hb    = (bf16*)take((size_t)4096 * 4096 * 2);
  float* bq3  = (float*)take((size_t)3072 * 4);
  float* bkv2 = (float*)take((size_t)2048 * 4);

  bf16* wt[8];
  for (int i = 0; i < 8; ++i) wt[i] = wt8 + (size_t)i * 1024 * 1024;

  const dim3 blk(256);
  PrepArgs pa;
  pa.wsq[0] = sa_wq; pa.wsq[1] = sa_wk; pa.wsq[2] = sa_wv; pa.wsq[3] = sa_wo;
  pa.wsq[4] = ca_wq; pa.wsq[5] = ca_wk; pa.wsq[6] = ca_wv; pa.wsq[7] = ca_wo;
  pa.w1 = mlp_w1; pa.w2 = mlp_w2; pa.xe = x_enc;
  pa.bs[0] = sa_bq; pa.bs[1] = sa_bk; pa.bs[2] = sa_bv;
  pa.bs[3] = ca_bk; pa.bs[4] = ca_bv;
  pa.wt8 = wt8; pa.w1t = w1t; pa.w2t = w2t; pa.xebf = xe_bf;
  pa.bq3 = bq3; pa.bkv2 = bkv2;
  prep_k<<<20485, blk, 0, stream>>>(pa);

  // ln1(x); fused [self QKV | cross KV]; both V transposes
  ln_k<float><<<4096, blk, 0, stream>>>(x, ln1_g, ln1_b, lnbuf);
  gemmqkv_k<<<dim3(40, 32), dim3(512), 0, stream>>>(lnbuf, xe_bf, wt[0], wt[5],
                                                    bq3, bkv2, Qb, Kb1, Vp1, Kb2, Vp2);
  vtrans_k<<<dim3(16, 64, 2), dim3(512), 0, stream>>>(Vp1, Vp2, Vt1, Vt2);

  // x1 = x + SelfAttn
  attn_k<<<dim3(8, 64), dim3(512), 0, stream>>>(Qb, Kb1, Vt1, AOb);
  gemm64_k<2><<<dim3(16, 32), dim3(512), 0, stream>>>(AOb, wt[3], sa_bo, x, x1, 1024, 1024);

  // x2 = x1 + CrossAttn(ln1(x1), x_encoder)
  ln_k<bf16><<<4096, blk, 0, stream>>>(x1, ln1_g, ln1_b, lnbuf);
  gemm64_k<0><<<dim3(16, 32), dim3(512), 0, stream>>>(lnbuf, wt[4], ca_bq, nullptr, Qb, 1024, 1024);
  attn_k<<<dim3(8, 64), dim3(512), 0, stream>>>(Qb, Kb2, Vt2, AOb);
  gemm64_k<4><<<dim3(16, 32), dim3(512), 0, stream>>>(AOb, wt[7], ca_bo, x1, x2, 1024, 1024);

  // out = x2 + MLP(ln2(x2))
  ln_k<bf16><<<4096, blk, 0, stream>>>(x2, ln2_g, ln2_b, lnbuf);
  gemm_k<3><<<dim3(32, 32), dim3(512), 0, stream>>>(lnbuf, w1t, mlp_b1, Hb, 1024, 4096);
  gemm64_k<5><<<dim3(16, 32), dim3(512), 0, stream>>>(Hb, w2t, mlp_b2, x2,
                                                      (float*)d_out, 4096, 1024);

  (void)in_sizes; (void)n_in; (void)out_size; (void)ws_size;
}